// Round 8
// baseline (608.505 us; speedup 1.0000x reference)
//
#include <hip/hip_runtime.h>
#include <cstddef>

#define EPSV 1e-5f

typedef __attribute__((ext_vector_type(8))) short frag8;   // 8 bf16 (4 VGPRs)
typedef __attribute__((ext_vector_type(4))) float f32x4;   // MFMA acc

__device__ __forceinline__ float lrelu01(float v) { return v > 0.f ? v : 0.01f * v; }
__device__ __forceinline__ void atomAddF(float* p, float v) { unsafeAtomicAdd(p, v); }
__device__ __forceinline__ unsigned fkey(float f) {
    unsigned u = __float_as_uint(f);
    return (u & 0x80000000u) ? ~u : (u | 0x80000000u);
}
__device__ __forceinline__ unsigned short f2b(float f) {  // RNE float->bf16
    unsigned u = __float_as_uint(f);
    unsigned r = u + 0x7fffu + ((u >> 16) & 1u);
    return (unsigned short)(r >> 16);
}
__device__ __forceinline__ float b2f(unsigned short h) {
    return __uint_as_float(((unsigned)h) << 16);
}
__device__ __forceinline__ float blo(unsigned u) { return __uint_as_float(u << 16); }
__device__ __forceinline__ float bhi(unsigned u) { return __uint_as_float(u & 0xffff0000u); }

static inline unsigned cdivu(unsigned a, unsigned b) { return (a + b - 1) / b; }

// ---------------- graph prep: degree+rank, dinv, CSR build ----------------

__global__ void k_degrank(const int* __restrict__ dst, int* __restrict__ deg,
                          int* __restrict__ rank, int E) {
    int e = blockIdx.x * 256 + threadIdx.x;
    if (e < E) rank[e] = atomicAdd(&deg[dst[e]], 1);
}

__global__ void k_dinv(const int* __restrict__ deg, float* __restrict__ dinv, int n) {
    int i = blockIdx.x * 256 + threadIdx.x;
    if (i < n) dinv[i] = rsqrtf((float)(deg[i] + 1));  // +1 self loop
}

__global__ void k_scan_local(const int* __restrict__ deg, int* __restrict__ startv,
                             int* __restrict__ bsum, int n) {
    __shared__ int t0[256];
    int tid = threadIdx.x;
    int i = blockIdx.x * 256 + tid;
    int v = (i < n) ? deg[i] : 0;
    t0[tid] = v;
    __syncthreads();
    for (int o = 1; o < 256; o <<= 1) {
        int add = (tid >= o) ? t0[tid - o] : 0;
        __syncthreads();
        t0[tid] += add;
        __syncthreads();
    }
    if (i < n) startv[i] = t0[tid] - v;
    if (tid == 255) bsum[blockIdx.x] = t0[255];
}

__global__ void k_scan_bsum(int* __restrict__ bsum, int nb) {
    __shared__ int t0[512];
    int tid = threadIdx.x;
    int v = (tid < nb) ? bsum[tid] : 0;
    t0[tid] = v;
    __syncthreads();
    for (int o = 1; o < 512; o <<= 1) {
        int add = (tid >= o) ? t0[tid - o] : 0;
        __syncthreads();
        t0[tid] += add;
        __syncthreads();
    }
    if (tid < nb) bsum[tid] = t0[tid] - v;
}

__global__ void k_scan_add(int* __restrict__ startv, const int* __restrict__ bsum, int n) {
    int i = blockIdx.x * 256 + threadIdx.x;
    if (i < n) startv[i] += bsum[blockIdx.x];
}

__global__ void k_fill(const int* __restrict__ src, const int* __restrict__ dst,
                       const int* __restrict__ rank, const int* __restrict__ startv,
                       int* __restrict__ csr, int E) {
    int e = blockIdx.x * 256 + threadIdx.x;
    if (e < E) csr[startv[dst[e]] + rank[e]] = src[e];
}

// ---------------- fused gather + LN (16-lane groups, dwordx4 rows) ----------------
template <int CH>
__launch_bounds__(256)
__global__ void k_gln(const int* __restrict__ startv, const int* __restrict__ degv,
                      const int* __restrict__ csr, const unsigned short* __restrict__ q,
                      const unsigned short* __restrict__ nf, const float* __restrict__ dinv,
                      const float* __restrict__ gcn_b, const float* __restrict__ lng,
                      const float* __restrict__ lnb, unsigned short* __restrict__ outp,
                      int ldo, int n) {
    const int wv = threadIdx.x >> 6, lane = threadIdx.x & 63;
    const int g = lane >> 4, p = lane & 15;
    int node = blockIdx.x * 4 + wv;
    if (node >= n) return;
    constexpr int CPL = CH / 16;   // channels per lane
    constexpr int DPL = CPL / 2;   // dwords per lane per row

    float acc[CPL];
#pragma unroll
    for (int k = 0; k < CPL; ++k) acc[k] = 0.f;

    {
        unsigned su[DPL];
        const unsigned short* qrow = q + (size_t)node * CH + p * CPL;
        if (DPL == 4) *(uint4*)su = *(const uint4*)qrow;
        else          *(uint2*)su = *(const uint2*)qrow;
        if (g == 0) {
#pragma unroll
            for (int d = 0; d < DPL; ++d) { acc[2 * d] += blo(su[d]); acc[2 * d + 1] += bhi(su[d]); }
        }
    }

    int s0 = startv[node], cnt = degv[node];
    int sidx[4];
#pragma unroll
    for (int t = 0; t < 4; ++t) { int j = t * 4 + g; sidx[t] = (j < cnt) ? csr[s0 + j] : 0; }
    for (int j0 = 0; j0 < cnt; j0 += 16) {
        unsigned buf[4][DPL];
#pragma unroll
        for (int t = 0; t < 4; ++t) {
            const unsigned short* src = q + (size_t)sidx[t] * CH + p * CPL;
            if (DPL == 4) *(uint4*)buf[t] = *(const uint4*)src;
            else          *(uint2*)buf[t] = *(const uint2*)src;
        }
        int nsidx[4];
#pragma unroll
        for (int t = 0; t < 4; ++t) {
            int j = j0 + 16 + t * 4 + g;
            nsidx[t] = (j < cnt) ? csr[s0 + j] : 0;
        }
#pragma unroll
        for (int t = 0; t < 4; ++t) {
            if (j0 + t * 4 + g < cnt) {
#pragma unroll
                for (int d = 0; d < DPL; ++d) {
                    acc[2 * d] += blo(buf[t][d]);
                    acc[2 * d + 1] += bhi(buf[t][d]);
                }
            }
        }
#pragma unroll
        for (int t = 0; t < 4; ++t) sidx[t] = nsidx[t];
    }

#pragma unroll
    for (int k = 0; k < CPL; ++k) {
        acc[k] += __shfl_xor(acc[k], 16);
        acc[k] += __shfl_xor(acc[k], 32);
    }

    float di = dinv[node];
    float nv[CPL], bv[CPL];
    {
        unsigned su[DPL];
        const unsigned short* nrow = nf + (size_t)node * CH + p * CPL;
        if (DPL == 4) *(uint4*)su = *(const uint4*)nrow;
        else          *(uint2*)su = *(const uint2*)nrow;
#pragma unroll
        for (int d = 0; d < DPL; ++d) { nv[2 * d] = blo(su[d]); nv[2 * d + 1] = bhi(su[d]); }
    }
    const float* gb = gcn_b + p * CPL;
#pragma unroll
    for (int k = 0; k < CPL; ++k) bv[k] = lrelu01(di * acc[k] + gb[k]);

    float s = 0.f, ss = 0.f;
#pragma unroll
    for (int k = 0; k < CPL; ++k) { s += nv[k] + bv[k]; ss += nv[k] * nv[k] + bv[k] * bv[k]; }
#pragma unroll
    for (int off = 32; off > 0; off >>= 1) { s += __shfl_xor(s, off); ss += __shfl_xor(ss, off); }
    const float inv = 1.f / (float)(8 * CH);  // 4x group replication * 2*CH channels
    float mu = s * inv;
    float var = ss * inv - mu * mu;
    float rsg = rsqrtf(var + EPSV);

    unsigned short* orow = outp + (size_t)node * ldo;
    if (g == 0) {
        unsigned short tmp[CPL];
        const float* lg = lng + p * CPL; const float* lb = lnb + p * CPL;
#pragma unroll
        for (int k = 0; k < CPL; ++k) tmp[k] = f2b((nv[k] - mu) * rsg * lg[k] + lb[k]);
        if (DPL == 4) *(uint4*)(orow + p * CPL) = *(uint4*)tmp;
        else          *(uint2*)(orow + p * CPL) = *(uint2*)tmp;
    } else if (g == 1) {
        unsigned short tmp[CPL];
        const float* lg = lng + CH + p * CPL; const float* lb = lnb + CH + p * CPL;
#pragma unroll
        for (int k = 0; k < CPL; ++k) tmp[k] = f2b((bv[k] - mu) * rsg * lg[k] + lb[k]);
        if (DPL == 4) *(uint4*)(orow + CH + p * CPL) = *(uint4*)tmp;
        else          *(uint2*)(orow + CH + p * CPL) = *(uint2*)tmp;
    }
}

// ---------------- small kernels ----------------

__global__ void k_wconv(const float* __restrict__ s0, const float* __restrict__ s1,
                        const float* __restrict__ s2, const float* __restrict__ s3,
                        const float* __restrict__ s4, const float* __restrict__ s5,
                        const float* __restrict__ s6, const float* __restrict__ s7,
                        unsigned short* __restrict__ dst) {
    int t = blockIdx.x * 256 + threadIdx.x;
    if (t >= 278528) return;
    const float* srcs[8] = {s0, s1, s2, s3, s4, s5, s6, s7};
    const int off[9] = {0, 8192, 139264, 143360, 147456, 163840, 180224, 196608, 278528};
    int seg = 0;
    while (t >= off[seg + 1]) ++seg;
    dst[t] = f2b(srcs[seg][t - off[seg]]);
}

__global__ void k_h1(const float* __restrict__ x, const float* __restrict__ w,
                     const float* __restrict__ b, unsigned short* __restrict__ h1, int n) {
    int node = blockIdx.x * 256 + threadIdx.x;
    if (node >= n) return;
    float x0 = x[node * 3], x1 = x[node * 3 + 1], x2 = x[node * 3 + 2];
    unsigned short* o = h1 + (size_t)node * 64;
#pragma unroll
    for (int cp = 0; cp < 8; ++cp) {
        unsigned short tmp[8];
#pragma unroll
        for (int t = 0; t < 8; ++t) {
            int c = cp * 8 + t;
            float v = x0 * w[c * 3] + x1 * w[c * 3 + 1] + x2 * w[c * 3 + 2] + b[c];
            tmp[t] = f2b(fmaxf(v, 0.f));
        }
        *(float4*)(o + cp * 8) = *(float4*)tmp;
    }
}

__global__ void k_murs(const float* __restrict__ sum2, const float* __restrict__ ss2,
                       float* __restrict__ mu2, float* __restrict__ rs2, float invn) {
    int c = threadIdx.x;  // 128
    float m = sum2[c] * invn;
    float var = ss2[c] * invn - m * m;
    mu2[c] = m;
    rs2[c] = rsqrtf(var + EPSV);
}

__global__ void k_g(const float* __restrict__ sum3, const float* __restrict__ ss3,
                    const unsigned* __restrict__ maxk, float* __restrict__ g, float invn) {
    int c = blockIdx.x * 256 + threadIdx.x;
    float m = sum3[c] * invn;
    float var = ss3[c] * invn - m * m;
    unsigned k = maxk[c];
    unsigned u = (k & 0x80000000u) ? (k & 0x7FFFFFFFu) : ~k;
    g[c] = fmaxf((__uint_as_float(u) - m) * rsqrtf(var + EPSV), 0.f);
}

__global__ void k_fc1(const float* __restrict__ g, const float* __restrict__ f1w,
                      const float* __restrict__ f1b, float* __restrict__ a1) {
    int row = blockIdx.x * 64 + (threadIdx.x >> 2);
    int part = threadIdx.x & 3;
    const float* w = f1w + (size_t)row * 1024 + part * 256;
    const float* gg = g + part * 256;
    float s = 0.f;
    for (int k = 0; k < 256; ++k) s = fmaf(w[k], gg[k], s);
    s += __shfl_xor(s, 1); s += __shfl_xor(s, 2);
    if (part == 0) a1[row] = fmaxf(s + f1b[row], 0.f);
}

__launch_bounds__(256)
__global__ void k_fc23(const float* __restrict__ a1, const float* __restrict__ f2w,
                       const float* __restrict__ f2b, const float* __restrict__ f3w,
                       const float* __restrict__ f3b, float* __restrict__ T9) {
    __shared__ float a2[256];
    int tid = threadIdx.x;
    {
        const float* w = f2w + (size_t)tid * 512;
        float s = f2b[tid];
        for (int k = 0; k < 512; ++k) s = fmaf(w[k], a1[k], s);
        a2[tid] = fmaxf(s, 0.f);
    }
    __syncthreads();
    if (tid < 9) {
        const float* w = f3w + (size_t)tid * 256;
        float s = f3b[tid];
        for (int k = 0; k < 256; ++k) s = fmaf(w[k], a2[k], s);
        if (tid == 0 || tid == 4 || tid == 8) s += 1.f;
        T9[tid] = s;
    }
}

__global__ void k_xg(const float* __restrict__ x, const float* __restrict__ T9,
                     const float* __restrict__ w, const float* __restrict__ b,
                     unsigned short* __restrict__ xg, int n) {
    int node = blockIdx.x * 256 + threadIdx.x;
    if (node >= n) return;
    float x0 = x[node * 3], x1 = x[node * 3 + 1], x2 = x[node * 3 + 2];
    float h0 = x0 * T9[0] + x1 * T9[3] + x2 * T9[6];
    float h1 = x0 * T9[1] + x1 * T9[4] + x2 * T9[7];
    float h2 = x0 * T9[2] + x1 * T9[5] + x2 * T9[8];
    unsigned short* o = xg + (size_t)node * 320;
#pragma unroll
    for (int cp = 0; cp < 8; ++cp) {
        unsigned short tmp[8];
#pragma unroll
        for (int t = 0; t < 8; ++t) {
            int c = cp * 8 + t;
            float v = h0 * w[c * 3] + h1 * w[c * 3 + 1] + h2 * w[c * 3 + 2] + b[c];
            tmp[t] = f2b(lrelu01(v));
        }
        *(float4*)(o + cp * 8) = *(float4*)tmp;
    }
}

__global__ void k_const4(const float* __restrict__ pooled, const float* __restrict__ ow,
                         const float* __restrict__ ob, float* __restrict__ c4, float invn) {
    int j = threadIdx.x >> 6, lane = threadIdx.x & 63;
    float s = 0.f;
    for (int c = lane; c < 256; c += 64) s += pooled[c] * invn * ow[j * 320 + c];
#pragma unroll
    for (int off = 32; off > 0; off >>= 1) s += __shfl_down(s, off);
    if (lane == 0) c4[j] = s + ob[j];
}

__global__ void k_out(const unsigned short* __restrict__ hcat, const float* __restrict__ ow,
                      const float* __restrict__ c4, float* __restrict__ out, int n) {
    int node = blockIdx.x * 256 + threadIdx.x;
    if (node >= n) return;
    const unsigned short* xgp = hcat + (size_t)node * 320 + 256;
    float s0 = c4[0], s1 = c4[1], s2 = c4[2], s3 = c4[3];
#pragma unroll
    for (int cp = 0; cp < 8; ++cp) {
        float4 raw = *(const float4*)(xgp + cp * 8);
        unsigned short tmp[8];
        *(float4*)tmp = raw;
#pragma unroll
        for (int t = 0; t < 8; ++t) {
            int k = 256 + cp * 8 + t;
            float f = b2f(tmp[t]);
            s0 = fmaf(f, ow[k], s0);
            s1 = fmaf(f, ow[320 + k], s1);
            s2 = fmaf(f, ow[640 + k], s2);
            s3 = fmaf(f, ow[960 + k], s3);
        }
    }
    *(float4*)(out + (size_t)node * 4) = make_float4(s0, s1, s2, s3);
}

// ---------------- MFMA bf16 GEMM (generic, BK=64: 32 MFMA per barrier-pair) ----------------
enum { MF_BIAS = 1, MF_LRELU = 2, MF_DINV = 4, MF_STOREF = 8, MF_STOREB = 16,
       MF_STATS = 32, MF_COLSUM = 64 };

template <int BN, int MODE>
__launch_bounds__(256)
__global__ void k_mgemm(const unsigned short* __restrict__ A, int lda, int K,
                        const unsigned short* __restrict__ W,  // [C][K]
                        const float* __restrict__ bias,
                        float* __restrict__ OutF, unsigned short* __restrict__ OutB, int ldo,
                        const float* __restrict__ dinv,
                        float* __restrict__ sum_o, float* __restrict__ ss_o,
                        unsigned* __restrict__ maxk_o) {
    constexpr int BM = 128;
    constexpr int LDT = 72;  // ushort stride per 64-k row; 36 dwords -> balanced 8/bank
    __shared__ unsigned short As[BM * LDT];
    __shared__ unsigned short Ws[BN * LDT];
    __shared__ float redS[2 * 128];
    __shared__ unsigned redM[128];

    const int tid = threadIdx.x;
    const int wid = tid >> 6, lane = tid & 63;
    const int quad = lane >> 4, lrow = lane & 15;
    const int bn0 = blockIdx.x * BM;
    const int bc0 = blockIdx.y * BN;

    constexpr int NI = (BN == 128) ? 4 : 2;
    constexpr int NJ = 4;
    const int wm = (BN == 128) ? (wid & 1) * 64 : wid * 32;
    const int wn = (BN == 128) ? (wid >> 1) * 64 : 0;

    if (MODE & (MF_STATS | MF_COLSUM)) {
        for (int c = tid; c < BN; c += 256) {
            redS[c] = 0.f; redS[128 + c] = 0.f; redM[c] = 0u;
        }
    }

    f32x4 acc[NI][NJ] = {};

    for (int k0 = 0; k0 < K; k0 += 64) {
#pragma unroll
        for (int h = 0; h < 4; ++h) {
            int ch = tid + h * 256;
            int row = ch >> 3, cp = ch & 7;
            *(float4*)&As[row * LDT + cp * 8] =
                *(const float4*)(A + (size_t)(bn0 + row) * lda + k0 + cp * 8);
        }
#pragma unroll
        for (int h = 0; h < BN / 32; ++h) {
            int ch = tid + h * 256;
            int row = ch >> 3, cp = ch & 7;
            *(float4*)&Ws[row * LDT + cp * 8] =
                *(const float4*)(W + (size_t)(bc0 + row) * K + k0 + cp * 8);
        }
        __syncthreads();
#pragma unroll
        for (int kc = 0; kc < 2; ++kc) {
            frag8 af[NI], bf[NJ];
#pragma unroll
            for (int i = 0; i < NI; ++i)
                af[i] = *(const frag8*)&As[(wm + i * 16 + lrow) * LDT + kc * 32 + quad * 8];
#pragma unroll
            for (int j = 0; j < NJ; ++j)
                bf[j] = *(const frag8*)&Ws[(wn + j * 16 + lrow) * LDT + kc * 32 + quad * 8];
#pragma unroll
            for (int i = 0; i < NI; ++i)
#pragma unroll
                for (int j = 0; j < NJ; ++j)
                    acc[i][j] = __builtin_amdgcn_mfma_f32_16x16x32_bf16(af[i], bf[j], acc[i][j], 0, 0, 0);
        }
        __syncthreads();
    }

#pragma unroll
    for (int j = 0; j < NJ; ++j) {
        const int col = bc0 + wn + j * 16 + lrow;
        float bv = (MODE & MF_BIAS) ? bias[col] : 0.f;
        float s = 0.f, q = 0.f, m = -3.4e38f;
#pragma unroll
        for (int i = 0; i < NI; ++i) {
            const int rowb = bn0 + wm + i * 16 + quad * 4;
#pragma unroll
            for (int r = 0; r < 4; ++r) {
                float t = acc[i][j][r] + bv;
                if (MODE & MF_LRELU) t = lrelu01(t);
                if (MODE & MF_DINV) t *= dinv[rowb + r];
                if (MODE & MF_STOREF) OutF[(size_t)(rowb + r) * ldo + col] = t;
                if (MODE & MF_STOREB) OutB[(size_t)(rowb + r) * ldo + col] = f2b(t);
                s += t; q += t * t; m = fmaxf(m, t);
            }
        }
        if (MODE & (MF_STATS | MF_COLSUM)) {
            s += __shfl_xor(s, 16); s += __shfl_xor(s, 32);
            if (MODE & MF_STATS) {
                q += __shfl_xor(q, 16); q += __shfl_xor(q, 32);
                m = fmaxf(m, __shfl_xor(m, 16)); m = fmaxf(m, __shfl_xor(m, 32));
            }
            if (quad == 0) {
                int lc = wn + j * 16 + lrow;
                atomicAdd(&redS[lc], s);
                if (MODE & MF_STATS) {
                    atomicAdd(&redS[128 + lc], q);
                    atomicMax(&redM[lc], fkey(m));
                }
            }
        }
    }
    if (MODE & (MF_STATS | MF_COLSUM)) {
        __syncthreads();
        for (int c = tid; c < BN; c += 256) {
            atomAddF(&sum_o[bc0 + c], redS[c]);
            if (MODE & MF_STATS) {
                atomAddF(&ss_o[bc0 + c], redS[128 + c]);
                atomicMax(&maxk_o[bc0 + c], redM[c]);
            }
        }
    }
}

// ---------------- fused li+gc (unchanged structure) ----------------
template <int BN>
__launch_bounds__(256)
__global__ void k_ligc(const unsigned short* __restrict__ A, int lda, int K,
                       const unsigned short* __restrict__ Wli, const float* __restrict__ bli,
                       const unsigned short* __restrict__ Wgc, const float* __restrict__ dinv,
                       unsigned short* __restrict__ NF, int ldnf,
                       unsigned short* __restrict__ Q, int ldq) {
    constexpr int BM = 128;
    constexpr int LDT = 40;
    constexpr int LDT2 = BN + 8;
    __shared__ unsigned short SA[BM * LDT2];
    __shared__ unsigned short Ws[BN * LDT];

    const int tid = threadIdx.x;
    const int wid = tid >> 6, lane = tid & 63;
    const int quad = lane >> 4, lrow = lane & 15;
    const int bn0 = blockIdx.x * BM;
    constexpr int NI = (BN == 128) ? 4 : 2;
    constexpr int NJ = 4;
    const int wm = (BN == 128) ? (wid & 1) * 64 : wid * 32;
    const int wn = (BN == 128) ? (wid >> 1) * 64 : 0;

    {
        f32x4 acc[NI][NJ] = {};
        for (int k0 = 0; k0 < K; k0 += 32) {
#pragma unroll
            for (int h = 0; h < 2; ++h) {
                int ch = tid + h * 256;
                int row = ch >> 2, cp = ch & 3;
                *(float4*)&SA[row * LDT + cp * 8] =
                    *(const float4*)(A + (size_t)(bn0 + row) * lda + k0 + cp * 8);
            }
#pragma unroll
            for (int h = 0; h < BN / 64; ++h) {
                int ch = tid + h * 256;
                int row = ch >> 2, cp = ch & 3;
                *(float4*)&Ws[row * LDT + cp * 8] =
                    *(const float4*)(Wli + (size_t)row * K + k0 + cp * 8);
            }
            __syncthreads();
            frag8 af[NI], bf[NJ];
#pragma unroll
            for (int i = 0; i < NI; ++i)
                af[i] = *(const frag8*)&SA[(wm + i * 16 + lrow) * LDT + quad * 8];
#pragma unroll
            for (int j = 0; j < NJ; ++j)
                bf[j] = *(const frag8*)&Ws[(wn + j * 16 + lrow) * LDT + quad * 8];
#pragma unroll
            for (int i = 0; i < NI; ++i)
#pragma unroll
                for (int j = 0; j < NJ; ++j)
                    acc[i][j] = __builtin_amdgcn_mfma_f32_16x16x32_bf16(af[i], bf[j], acc[i][j], 0, 0, 0);
            __syncthreads();
        }
#pragma unroll
        for (int j = 0; j < NJ; ++j) {
            const int col = wn + j * 16 + lrow;
            float bv = bli[col];
#pragma unroll
            for (int i = 0; i < NI; ++i) {
                const int rowl = wm + i * 16 + quad * 4;
#pragma unroll
                for (int r = 0; r < 4; ++r) {
                    unsigned short h = f2b(lrelu01(acc[i][j][r] + bv));
                    NF[(size_t)(bn0 + rowl + r) * ldnf + col] = h;
                    SA[(rowl + r) * LDT2 + col] = h;
                }
            }
        }
        __syncthreads();
    }
    {
        f32x4 acc[NI][NJ] = {};
        for (int k0 = 0; k0 < BN; k0 += 32) {
#pragma unroll
            for (int h = 0; h < BN / 64; ++h) {
                int ch = tid + h * 256;
                int row = ch >> 2, cp = ch & 3;
                *(float4*)&Ws[row * LDT + cp * 8] =
                    *(const float4*)(Wgc + (size_t)row * BN + k0 + cp * 8);
            }
            __syncthreads();
            frag8 af[NI], bf[NJ];
#pragma unroll
            for (int i = 0; i < NI; ++i)
                af[i] = *(const frag8*)&SA[(wm + i * 16 + lrow) * LDT2 + k0 + quad * 8];
#pragma unroll
            for (int j = 0; j < NJ; ++j)
                bf[j] = *(const frag8*)&Ws[(wn + j * 16 + lrow) * LDT + quad * 8];
#pragma unroll
            for (int i = 0; i < NI; ++i)
#pragma unroll
                for (int j = 0; j < NJ; ++j)
                    acc[i][j] = __builtin_amdgcn_mfma_f32_16x16x32_bf16(af[i], bf[j], acc[i][j], 0, 0, 0);
            __syncthreads();
        }
#pragma unroll
        for (int j = 0; j < NJ; ++j) {
            const int col = wn + j * 16 + lrow;
#pragma unroll
            for (int i = 0; i < NI; ++i) {
                const int rowb = bn0 + wm + i * 16 + quad * 4;
#pragma unroll
                for (int r = 0; r < 4; ++r) {
                    float t = acc[i][j][r] * dinv[rowb + r];
                    Q[(size_t)(rowb + r) * ldq + col] = f2b(t);
                }
            }
        }
    }
}

// ---------------- z3 stats GEMM v2 ----------------
// A-tile (128x128) resident in LDS with fused BN-normalize during staging (kills prebn);
// W staged 64 channels at a time (LDS 52 KB -> 3 blocks/CU); 32 MFMA per barrier-pair;
// stats epilogue = wave shfl + direct global atomics (no epilogue barriers).
__launch_bounds__(256)
__global__ void k_z3(const float* __restrict__ Z, const float* __restrict__ mu,
                     const float* __restrict__ rs,
                     const unsigned short* __restrict__ W,   // [1024,128] bf16
                     const float* __restrict__ bias,         // [1024]
                     float* __restrict__ sum_o, float* __restrict__ ss_o,
                     unsigned* __restrict__ maxk_o) {
    constexpr int LDT = 136;  // ushort stride for 128-k rows; 68 dwords -> balanced banks
    __shared__ unsigned short As[128 * LDT];  // 34816 B
    __shared__ unsigned short Ws[64 * LDT];   // 17408 B

    const int tid = threadIdx.x;
    const int wid = tid >> 6, lane = tid & 63;
    const int quad = lane >> 4, lrow = lane & 15;
    const int bn0 = blockIdx.x * 128;
    const int wm = (wid & 1) * 64;   // 64-row half
    const int wn = (wid >> 1) * 32;  // 32-col half of the 64-col W tile

    // stage A3 = bf16(relu((z2 - mu) * rs)), full 128x128 tile, once
#pragma unroll
    for (int h = 0; h < 8; ++h) {
        int ch = tid + h * 256;
        int row = ch >> 4, cp = ch & 15;
        const float* src = Z + (size_t)(bn0 + row) * 128 + cp * 8;
        float4 v0 = *(const float4*)src;
        float4 v1 = *(const float4*)(src + 4);
        int c = cp * 8;
        unsigned short t[8];
        t[0] = f2b(fmaxf((v0.x - mu[c + 0]) * rs[c + 0], 0.f));
        t[1] = f2b(fmaxf((v0.y - mu[c + 1]) * rs[c + 1], 0.f));
        t[2] = f2b(fmaxf((v0.z - mu[c + 2]) * rs[c + 2], 0.f));
        t[3] = f2b(fmaxf((v0.w - mu[c + 3]) * rs[c + 3], 0.f));
        t[4] = f2b(fmaxf((v1.x - mu[c + 4]) * rs[c + 4], 0.f));
        t[5] = f2b(fmaxf((v1.y - mu[c + 5]) * rs[c + 5], 0.f));
        t[6] = f2b(fmaxf((v1.z - mu[c + 6]) * rs[c + 6], 0.f));
        t[7] = f2b(fmaxf((v1.w - mu[c + 7]) * rs[c + 7], 0.f));
        *(float4*)&As[row * LDT + cp * 8] = *(float4*)t;
    }

    for (int cb = 0; cb < 16; ++cb) {
        // stage W 64-channel block (64 rows x 128 k): 1024 chunks, 4/thread
#pragma unroll
        for (int h = 0; h < 4; ++h) {
            int ch = tid + h * 256;
            int row = ch >> 4, cp = ch & 15;
            *(float4*)&Ws[row * LDT + cp * 8] =
                *(const float4*)(W + (size_t)(cb * 64 + row) * 128 + cp * 8);
        }
        __syncthreads();
        f32x4 acc[4][2] = {};
#pragma unroll
        for (int kc = 0; kc < 4; ++kc) {
            frag8 af[4], bf[2];
#pragma unroll
            for (int i = 0; i < 4; ++i)
                af[i] = *(const frag8*)&As[(wm + i * 16 + lrow) * LDT + kc * 32 + quad * 8];
#pragma unroll
            for (int j = 0; j < 2; ++j)
                bf[j] = *(const frag8*)&Ws[(wn + j * 16 + lrow) * LDT + kc * 32 + quad * 8];
#pragma unroll
            for (int i = 0; i < 4; ++i)
#pragma unroll
                for (int j = 0; j < 2; ++j)
                    acc[i][j] = __builtin_amdgcn_mfma_f32_16x16x32_bf16(af[i], bf[j], acc[i][j], 0, 0, 0);
        }
        // stats epilogue: shfl reduce (no LDS, no barrier), direct global atomics
#pragma unroll
        for (int j = 0; j < 2; ++j) {
            int c = cb * 64 + wn + j * 16 + lrow;
            float bv = bias[c];
            float s = 0.f, q = 0.f, m = -3.4e38f;
#pragma unroll
            for (int i = 0; i < 4; ++i)
#pragma unroll
                for (int r = 0; r < 4; ++r) {
                    float t = acc[i][j][r] + bv;
                    s += t; q += t * t; m = fmaxf(m, t);
                }
            s += __shfl_xor(s, 16); s += __shfl_xor(s, 32);
            q += __shfl_xor(q, 16); q += __shfl_xor(q, 32);
            m = fmaxf(m, __shfl_xor(m, 16)); m = fmaxf(m, __shfl_xor(m, 32));
            if (quad == 0) {
                atomAddF(&sum_o[c], s);
                atomAddF(&ss_o[c], q);
                atomicMax(&maxk_o[c], fkey(m));
            }
        }
        __syncthreads();  // all waves done reading Ws before restage
    }
}

// ---------------- launch ----------------
// Buffer lifetimes:
//   F1 [N,128]f32: z2 only (z3 stages+normalizes directly from it; prebn removed)
//   B1 [N,64] u16: h1 -> nf1
//   B2 [N,128]u16: q1 (first N*64) -> hmid -> q2 (in-place over hmid)
//   B3 [N,128]u16: hln1 -> nf2
//   H  [N,320]u16: xg cols 256.. (early), LN2 out cols 0..255 (late)

extern "C" void kernel_launch(void* const* d_in, const int* in_sizes, int n_in,
                              void* d_out, int out_size, void* d_ws, size_t ws_size,
                              hipStream_t stream) {
    const float* x   = (const float*)d_in[0];
    const int*   ei  = (const int*)d_in[1];
    const float* c1w = (const float*)d_in[2];  const float* c1b = (const float*)d_in[3];
    const float* c2w = (const float*)d_in[4];  const float* c2b = (const float*)d_in[5];
    const float* c3w = (const float*)d_in[6];  const float* c3b = (const float*)d_in[7];
    const float* f1w = (const float*)d_in[8];  const float* f1b = (const float*)d_in[9];
    const float* f2w = (const float*)d_in[10]; const float* f2b = (const float*)d_in[11];
    const float* f3w = (const float*)d_in[12]; const float* f3b = (const float*)d_in[13];
    const float* cv1w = (const float*)d_in[14]; const float* cv1b = (const float*)d_in[15];
    const float* li1w = (const float*)d_in[16]; const float* li1b = (const float*)d_in[17];
    const float* gc1w = (const float*)d_in[18]; const float* gc1b = (const float*)d_in[19];
    const float* ln1g = (const float*)d_in[20]; const float* ln1b = (const float*)d_in[21];
    const float* cv2w = (const float*)d_in[22]; const float* cv2b = (const float*)d_in[23];
    const float* li2w = (const float*)d_in[24]; const float* li2b = (const float*)d_in[25];
    const float* gc2w = (const float*)d_in[26]; const float* gc2b = (const float*)d_in[27];
    const float* ln2g = (const float*)d_in[28]; const float* ln2b = (const float*)d_in[29];
    const float* cv3w = (const float*)d_in[30]; const float* cv3b = (const float*)d_in[31];
    const float* ow  = (const float*)d_in[32]; const float* ob  = (const float*)d_in[33];
    float* out = (float*)d_out;

    const int N = in_sizes[0] / 3;
    const int E = in_sizes[1] / 2;
    const int* srcI = ei;
    const int* dstI = ei + E;

    char* base = (char*)d_ws;
    size_t off = 0;
    auto take = [&](size_t bytes) -> char* {
        char* p = base + off;
        off = (off + bytes + 255) & ~(size_t)255;
        return p;
    };
    int*   deg    = (int*)  take((size_t)N * 4);
    float* dinv   = (float*)take((size_t)N * 4);
    int*   startv = (int*)  take((size_t)N * 4);
    int*   rank   = (int*)  take((size_t)E * 4);
    int*   csr    = (int*)  take((size_t)E * 4);
    int*   bsum   = (int*)  take(512 * 4);
    float* sm     = (float*)take(8192 * 4);
    unsigned short* WB = (unsigned short*)take(278528 * 2);
    unsigned short* H  = (unsigned short*)take((size_t)N * 320 * 2);
    float* F1 = (float*)take((size_t)N * 128 * 4);
    unsigned short* B1 = (unsigned short*)take((size_t)N * 64 * 2);
    unsigned short* B2 = (unsigned short*)take((size_t)N * 128 * 2);
    unsigned short* B3 = (unsigned short*)take((size_t)N * 128 * 2);

    unsigned short* c2wb  = WB + 0;
    unsigned short* c3wb  = WB + 8192;
    unsigned short* li1wb = WB + 139264;
    unsigned short* gc1wb = WB + 143360;
    unsigned short* cv2wb = WB + 147456;
    unsigned short* li2wb = WB + 163840;
    unsigned short* gc2wb = WB + 180224;
    unsigned short* cv3wb = WB + 196608;

    float* sum2 = sm + 0;    float* ss2 = sm + 128;
    float* sum3 = sm + 256;  float* ss3 = sm + 1280;
    unsigned* maxk = (unsigned*)(sm + 2304);
    float* pooled = sm + 3328;
    unsigned* dmax = (unsigned*)(sm + 3584);
    float* mu2 = sm + 3712; float* rs2 = sm + 3840;
    float* T9  = sm + 3968; float* c4 = sm + 3984;
    float* gbuf = sm + 4096;
    float* a1   = sm + 5120;

    const float invn = 1.0f / (float)N;
    const dim3 blk(256);
    const unsigned GX = (unsigned)(N / 128);
    const unsigned NB = cdivu((unsigned)N, 256);

    hipMemsetAsync(deg, 0, (size_t)N * 4, stream);
    hipMemsetAsync(sm, 0, 3712 * 4, stream);

    // ---- graph prep ----
    k_degrank<<<cdivu(E, 256), blk, 0, stream>>>(dstI, deg, rank, E);
    k_dinv<<<cdivu(N, 256), blk, 0, stream>>>(deg, dinv, N);
    k_scan_local<<<NB, blk, 0, stream>>>(deg, startv, bsum, N);
    k_scan_bsum<<<1, 512, 0, stream>>>(bsum, (int)NB);
    k_scan_add<<<NB, blk, 0, stream>>>(startv, bsum, N);
    k_fill<<<cdivu(E, 256), blk, 0, stream>>>(srcI, dstI, rank, startv, csr, E);

    k_wconv<<<cdivu(278528, 256), blk, 0, stream>>>(c2w, c3w, li1w, gc1w, cv2w, li2w, gc2w, cv3w, WB);

    // ---- TNet ----
    k_h1<<<cdivu((unsigned)N, 256), blk, 0, stream>>>(x, c1w, c1b, B1, N);
    k_mgemm<128, (MF_BIAS | MF_STOREF | MF_STATS)><<<dim3(GX, 1), blk, 0, stream>>>(
        B1, 64, 64, c2wb, c2b, F1, nullptr, 128, nullptr, sum2, ss2, dmax);
    k_murs<<<1, 128, 0, stream>>>(sum2, ss2, mu2, rs2, invn);
    k_z3<<<GX, blk, 0, stream>>>(F1, mu2, rs2, c3wb, c3b, sum3, ss3, maxk);
    k_g<<<4, blk, 0, stream>>>(sum3, ss3, maxk, gbuf, invn);
    k_fc1<<<8, blk, 0, stream>>>(gbuf, f1w, f1b, a1);
    k_fc23<<<1, blk, 0, stream>>>(a1, f2w, f2b, f3w, f3b, T9);
    k_xg<<<cdivu((unsigned)N, 256), blk, 0, stream>>>(x, T9, cv1w, cv1b, H + 256, N);

    // ---- GCN block 1 (C=64) ----
    k_ligc<64><<<GX, blk, 0, stream>>>(H + 256, 320, 64, li1wb, li1b, gc1wb, dinv, B1, 64, B2, 64);
    k_gln<64><<<cdivu((unsigned)N, 4), blk, 0, stream>>>(
        startv, deg, csr, B2, B1, dinv, gc1b, ln1g, ln1b, B3, 128, N);
    k_mgemm<128, (MF_BIAS | MF_LRELU | MF_STOREB)><<<dim3(GX, 1), blk, 0, stream>>>(
        B3, 128, 128, cv2wb, cv2b, nullptr, B2, 128, nullptr, nullptr, nullptr, nullptr);

    // ---- GCN block 2 (C=128) ----
    k_ligc<128><<<GX, blk, 0, stream>>>(B2, 128, 128, li2wb, li2b, gc2wb, dinv, B3, 128, B2, 128);
    k_gln<128><<<cdivu((unsigned)N, 4), blk, 0, stream>>>(
        startv, deg, csr, B2, B3, dinv, gc2b, ln2g, ln2b, H, 320, N);

    // ---- conv3 (K=320 -> 256) fused column-sum only ----
    k_mgemm<128, (MF_BIAS | MF_LRELU | MF_COLSUM)><<<dim3(GX, 2), blk, 0, stream>>>(
        H, 320, 320, cv3wb, cv3b, nullptr, nullptr, 0, nullptr, pooled, nullptr, nullptr);

    // ---- head ----
    k_const4<<<1, 256, 0, stream>>>(pooled, ow, ob, c4, invn);
    k_out<<<cdivu((unsigned)N, 256), blk, 0, stream>>>(H, ow, c4, out, N);
}

// Round 9
// 575.416 us; speedup vs baseline: 1.0575x; 1.0575x over previous
//
#include <hip/hip_runtime.h>
#include <cstddef>

#define EPSV 1e-5f

typedef __attribute__((ext_vector_type(8))) short frag8;   // 8 bf16 (4 VGPRs)
typedef __attribute__((ext_vector_type(4))) float f32x4;   // MFMA acc

__device__ __forceinline__ float lrelu01(float v) { return v > 0.f ? v : 0.01f * v; }
__device__ __forceinline__ void atomAddF(float* p, float v) { unsafeAtomicAdd(p, v); }
__device__ __forceinline__ unsigned fkey(float f) {
    unsigned u = __float_as_uint(f);
    return (u & 0x80000000u) ? ~u : (u | 0x80000000u);
}
__device__ __forceinline__ unsigned short f2b(float f) {  // RNE float->bf16
    unsigned u = __float_as_uint(f);
    unsigned r = u + 0x7fffu + ((u >> 16) & 1u);
    return (unsigned short)(r >> 16);
}
__device__ __forceinline__ float b2f(unsigned short h) {
    return __uint_as_float(((unsigned)h) << 16);
}
__device__ __forceinline__ float blo(unsigned u) { return __uint_as_float(u << 16); }
__device__ __forceinline__ float bhi(unsigned u) { return __uint_as_float(u & 0xffff0000u); }

static inline unsigned cdivu(unsigned a, unsigned b) { return (a + b - 1) / b; }

// ---------------- graph prep: degree+rank, dinv, CSR build ----------------

__global__ void k_degrank(const int* __restrict__ dst, int* __restrict__ deg,
                          int* __restrict__ rank, int E) {
    int e = blockIdx.x * 256 + threadIdx.x;
    if (e < E) rank[e] = atomicAdd(&deg[dst[e]], 1);
}

__global__ void k_dinv(const int* __restrict__ deg, float* __restrict__ dinv, int n) {
    int i = blockIdx.x * 256 + threadIdx.x;
    if (i < n) dinv[i] = rsqrtf((float)(deg[i] + 1));  // +1 self loop
}

__global__ void k_scan_local(const int* __restrict__ deg, int* __restrict__ startv,
                             int* __restrict__ bsum, int n) {
    __shared__ int t0[256];
    int tid = threadIdx.x;
    int i = blockIdx.x * 256 + tid;
    int v = (i < n) ? deg[i] : 0;
    t0[tid] = v;
    __syncthreads();
    for (int o = 1; o < 256; o <<= 1) {
        int add = (tid >= o) ? t0[tid - o] : 0;
        __syncthreads();
        t0[tid] += add;
        __syncthreads();
    }
    if (i < n) startv[i] = t0[tid] - v;
    if (tid == 255) bsum[blockIdx.x] = t0[255];
}

__global__ void k_scan_bsum(int* __restrict__ bsum, int nb) {
    __shared__ int t0[512];
    int tid = threadIdx.x;
    int v = (tid < nb) ? bsum[tid] : 0;
    t0[tid] = v;
    __syncthreads();
    for (int o = 1; o < 512; o <<= 1) {
        int add = (tid >= o) ? t0[tid - o] : 0;
        __syncthreads();
        t0[tid] += add;
        __syncthreads();
    }
    if (tid < nb) bsum[tid] = t0[tid] - v;
}

__global__ void k_scan_add(int* __restrict__ startv, const int* __restrict__ bsum, int n) {
    int i = blockIdx.x * 256 + threadIdx.x;
    if (i < n) startv[i] += bsum[blockIdx.x];
}

__global__ void k_fill(const int* __restrict__ src, const int* __restrict__ dst,
                       const int* __restrict__ rank, const int* __restrict__ startv,
                       int* __restrict__ csr, int E) {
    int e = blockIdx.x * 256 + threadIdx.x;
    if (e < E) csr[startv[dst[e]] + rank[e]] = src[e];
}

// ---------------- fused gather + LN (16-lane groups, dwordx4 rows) ----------------
template <int CH>
__launch_bounds__(256)
__global__ void k_gln(const int* __restrict__ startv, const int* __restrict__ degv,
                      const int* __restrict__ csr, const unsigned short* __restrict__ q,
                      const unsigned short* __restrict__ nf, const float* __restrict__ dinv,
                      const float* __restrict__ gcn_b, const float* __restrict__ lng,
                      const float* __restrict__ lnb, unsigned short* __restrict__ outp,
                      int ldo, int n) {
    const int wv = threadIdx.x >> 6, lane = threadIdx.x & 63;
    const int g = lane >> 4, p = lane & 15;
    int node = blockIdx.x * 4 + wv;
    if (node >= n) return;
    constexpr int CPL = CH / 16;   // channels per lane
    constexpr int DPL = CPL / 2;   // dwords per lane per row

    float acc[CPL];
#pragma unroll
    for (int k = 0; k < CPL; ++k) acc[k] = 0.f;

    {
        unsigned su[DPL];
        const unsigned short* qrow = q + (size_t)node * CH + p * CPL;
        if (DPL == 4) *(uint4*)su = *(const uint4*)qrow;
        else          *(uint2*)su = *(const uint2*)qrow;
        if (g == 0) {
#pragma unroll
            for (int d = 0; d < DPL; ++d) { acc[2 * d] += blo(su[d]); acc[2 * d + 1] += bhi(su[d]); }
        }
    }

    int s0 = startv[node], cnt = degv[node];
    int sidx[4];
#pragma unroll
    for (int t = 0; t < 4; ++t) { int j = t * 4 + g; sidx[t] = (j < cnt) ? csr[s0 + j] : 0; }
    for (int j0 = 0; j0 < cnt; j0 += 16) {
        unsigned buf[4][DPL];
#pragma unroll
        for (int t = 0; t < 4; ++t) {
            const unsigned short* src = q + (size_t)sidx[t] * CH + p * CPL;
            if (DPL == 4) *(uint4*)buf[t] = *(const uint4*)src;
            else          *(uint2*)buf[t] = *(const uint2*)src;
        }
        int nsidx[4];
#pragma unroll
        for (int t = 0; t < 4; ++t) {
            int j = j0 + 16 + t * 4 + g;
            nsidx[t] = (j < cnt) ? csr[s0 + j] : 0;
        }
#pragma unroll
        for (int t = 0; t < 4; ++t) {
            if (j0 + t * 4 + g < cnt) {
#pragma unroll
                for (int d = 0; d < DPL; ++d) {
                    acc[2 * d] += blo(buf[t][d]);
                    acc[2 * d + 1] += bhi(buf[t][d]);
                }
            }
        }
#pragma unroll
        for (int t = 0; t < 4; ++t) sidx[t] = nsidx[t];
    }

#pragma unroll
    for (int k = 0; k < CPL; ++k) {
        acc[k] += __shfl_xor(acc[k], 16);
        acc[k] += __shfl_xor(acc[k], 32);
    }

    float di = dinv[node];
    float nv[CPL], bv[CPL];
    {
        unsigned su[DPL];
        const unsigned short* nrow = nf + (size_t)node * CH + p * CPL;
        if (DPL == 4) *(uint4*)su = *(const uint4*)nrow;
        else          *(uint2*)su = *(const uint2*)nrow;
#pragma unroll
        for (int d = 0; d < DPL; ++d) { nv[2 * d] = blo(su[d]); nv[2 * d + 1] = bhi(su[d]); }
    }
    const float* gb = gcn_b + p * CPL;
#pragma unroll
    for (int k = 0; k < CPL; ++k) bv[k] = lrelu01(di * acc[k] + gb[k]);

    float s = 0.f, ss = 0.f;
#pragma unroll
    for (int k = 0; k < CPL; ++k) { s += nv[k] + bv[k]; ss += nv[k] * nv[k] + bv[k] * bv[k]; }
#pragma unroll
    for (int off = 32; off > 0; off >>= 1) { s += __shfl_xor(s, off); ss += __shfl_xor(ss, off); }
    const float inv = 1.f / (float)(8 * CH);  // 4x group replication * 2*CH channels
    float mu = s * inv;
    float var = ss * inv - mu * mu;
    float rsg = rsqrtf(var + EPSV);

    unsigned short* orow = outp + (size_t)node * ldo;
    if (g == 0) {
        unsigned short tmp[CPL];
        const float* lg = lng + p * CPL; const float* lb = lnb + p * CPL;
#pragma unroll
        for (int k = 0; k < CPL; ++k) tmp[k] = f2b((nv[k] - mu) * rsg * lg[k] + lb[k]);
        if (DPL == 4) *(uint4*)(orow + p * CPL) = *(uint4*)tmp;
        else          *(uint2*)(orow + p * CPL) = *(uint2*)tmp;
    } else if (g == 1) {
        unsigned short tmp[CPL];
        const float* lg = lng + CH + p * CPL; const float* lb = lnb + CH + p * CPL;
#pragma unroll
        for (int k = 0; k < CPL; ++k) tmp[k] = f2b((bv[k] - mu) * rsg * lg[k] + lb[k]);
        if (DPL == 4) *(uint4*)(orow + CH + p * CPL) = *(uint4*)tmp;
        else          *(uint2*)(orow + CH + p * CPL) = *(uint2*)tmp;
    }
}

// ---------------- small kernels ----------------

__global__ void k_wconv(const float* __restrict__ s0, const float* __restrict__ s1,
                        const float* __restrict__ s2, const float* __restrict__ s3,
                        const float* __restrict__ s4, const float* __restrict__ s5,
                        const float* __restrict__ s6, const float* __restrict__ s7,
                        unsigned short* __restrict__ dst) {
    int t = blockIdx.x * 256 + threadIdx.x;
    if (t >= 278528) return;
    const float* srcs[8] = {s0, s1, s2, s3, s4, s5, s6, s7};
    const int off[9] = {0, 8192, 139264, 143360, 147456, 163840, 180224, 196608, 278528};
    int seg = 0;
    while (t >= off[seg + 1]) ++seg;
    dst[t] = f2b(srcs[seg][t - off[seg]]);
}

__global__ void k_h1(const float* __restrict__ x, const float* __restrict__ w,
                     const float* __restrict__ b, unsigned short* __restrict__ h1, int n) {
    int node = blockIdx.x * 256 + threadIdx.x;
    if (node >= n) return;
    float x0 = x[node * 3], x1 = x[node * 3 + 1], x2 = x[node * 3 + 2];
    unsigned short* o = h1 + (size_t)node * 64;
#pragma unroll
    for (int cp = 0; cp < 8; ++cp) {
        unsigned short tmp[8];
#pragma unroll
        for (int t = 0; t < 8; ++t) {
            int c = cp * 8 + t;
            float v = x0 * w[c * 3] + x1 * w[c * 3 + 1] + x2 * w[c * 3 + 2] + b[c];
            tmp[t] = f2b(fmaxf(v, 0.f));
        }
        *(float4*)(o + cp * 8) = *(float4*)tmp;
    }
}

__global__ void k_murs(const float* __restrict__ sum2, const float* __restrict__ ss2,
                       float* __restrict__ mu2, float* __restrict__ rs2, float invn) {
    int c = threadIdx.x;  // 128
    float m = sum2[c] * invn;
    float var = ss2[c] * invn - m * m;
    mu2[c] = m;
    rs2[c] = rsqrtf(var + EPSV);
}

// A3 = bf16(relu((z2 - mu)*rs)), z2 fp32 [N,128]
__global__ void k_prebn(const float* __restrict__ z, const float* __restrict__ mu,
                        const float* __restrict__ rs, unsigned short* __restrict__ a3,
                        int total) {
    int t = (blockIdx.x * 256 + threadIdx.x) * 4;
    if (t >= total) return;
    int c = t & 127;
    float4 v = *(const float4*)(z + t);
    ushort4 o;
    o.x = f2b(fmaxf((v.x - mu[c + 0]) * rs[c + 0], 0.f));
    o.y = f2b(fmaxf((v.y - mu[c + 1]) * rs[c + 1], 0.f));
    o.z = f2b(fmaxf((v.z - mu[c + 2]) * rs[c + 2], 0.f));
    o.w = f2b(fmaxf((v.w - mu[c + 3]) * rs[c + 3], 0.f));
    *(ushort4*)(a3 + t) = o;
}

__global__ void k_g(const float* __restrict__ sum3, const float* __restrict__ ss3,
                    const unsigned* __restrict__ maxk, float* __restrict__ g, float invn) {
    int c = blockIdx.x * 256 + threadIdx.x;
    float m = sum3[c] * invn;
    float var = ss3[c] * invn - m * m;
    unsigned k = maxk[c];
    unsigned u = (k & 0x80000000u) ? (k & 0x7FFFFFFFu) : ~k;
    g[c] = fmaxf((__uint_as_float(u) - m) * rsqrtf(var + EPSV), 0.f);
}

__global__ void k_fc1(const float* __restrict__ g, const float* __restrict__ f1w,
                      const float* __restrict__ f1b, float* __restrict__ a1) {
    int row = blockIdx.x * 64 + (threadIdx.x >> 2);
    int part = threadIdx.x & 3;
    const float* w = f1w + (size_t)row * 1024 + part * 256;
    const float* gg = g + part * 256;
    float s = 0.f;
    for (int k = 0; k < 256; ++k) s = fmaf(w[k], gg[k], s);
    s += __shfl_xor(s, 1); s += __shfl_xor(s, 2);
    if (part == 0) a1[row] = fmaxf(s + f1b[row], 0.f);
}

__launch_bounds__(256)
__global__ void k_fc23(const float* __restrict__ a1, const float* __restrict__ f2w,
                       const float* __restrict__ f2b, const float* __restrict__ f3w,
                       const float* __restrict__ f3b, float* __restrict__ T9) {
    __shared__ float a2[256];
    int tid = threadIdx.x;
    {
        const float* w = f2w + (size_t)tid * 512;
        float s = f2b[tid];
        for (int k = 0; k < 512; ++k) s = fmaf(w[k], a1[k], s);
        a2[tid] = fmaxf(s, 0.f);
    }
    __syncthreads();
    if (tid < 9) {
        const float* w = f3w + (size_t)tid * 256;
        float s = f3b[tid];
        for (int k = 0; k < 256; ++k) s = fmaf(w[k], a2[k], s);
        if (tid == 0 || tid == 4 || tid == 8) s += 1.f;
        T9[tid] = s;
    }
}

__global__ void k_xg(const float* __restrict__ x, const float* __restrict__ T9,
                     const float* __restrict__ w, const float* __restrict__ b,
                     unsigned short* __restrict__ xg, int n) {
    int node = blockIdx.x * 256 + threadIdx.x;
    if (node >= n) return;
    float x0 = x[node * 3], x1 = x[node * 3 + 1], x2 = x[node * 3 + 2];
    float h0 = x0 * T9[0] + x1 * T9[3] + x2 * T9[6];
    float h1 = x0 * T9[1] + x1 * T9[4] + x2 * T9[7];
    float h2 = x0 * T9[2] + x1 * T9[5] + x2 * T9[8];
    unsigned short* o = xg + (size_t)node * 320;
#pragma unroll
    for (int cp = 0; cp < 8; ++cp) {
        unsigned short tmp[8];
#pragma unroll
        for (int t = 0; t < 8; ++t) {
            int c = cp * 8 + t;
            float v = h0 * w[c * 3] + h1 * w[c * 3 + 1] + h2 * w[c * 3 + 2] + b[c];
            tmp[t] = f2b(lrelu01(v));
        }
        *(float4*)(o + cp * 8) = *(float4*)tmp;
    }
}

__global__ void k_const4(const float* __restrict__ pooled, const float* __restrict__ ow,
                         const float* __restrict__ ob, float* __restrict__ c4, float invn) {
    int j = threadIdx.x >> 6, lane = threadIdx.x & 63;
    float s = 0.f;
    for (int c = lane; c < 256; c += 64) s += pooled[c] * invn * ow[j * 320 + c];
#pragma unroll
    for (int off = 32; off > 0; off >>= 1) s += __shfl_down(s, off);
    if (lane == 0) c4[j] = s + ob[j];
}

__global__ void k_out(const unsigned short* __restrict__ hcat, const float* __restrict__ ow,
                      const float* __restrict__ c4, float* __restrict__ out, int n) {
    int node = blockIdx.x * 256 + threadIdx.x;
    if (node >= n) return;
    const unsigned short* xgp = hcat + (size_t)node * 320 + 256;
    float s0 = c4[0], s1 = c4[1], s2 = c4[2], s3 = c4[3];
#pragma unroll
    for (int cp = 0; cp < 8; ++cp) {
        float4 raw = *(const float4*)(xgp + cp * 8);
        unsigned short tmp[8];
        *(float4*)tmp = raw;
#pragma unroll
        for (int t = 0; t < 8; ++t) {
            int k = 256 + cp * 8 + t;
            float f = b2f(tmp[t]);
            s0 = fmaf(f, ow[k], s0);
            s1 = fmaf(f, ow[320 + k], s1);
            s2 = fmaf(f, ow[640 + k], s2);
            s3 = fmaf(f, ow[960 + k], s3);
        }
    }
    *(float4*)(out + (size_t)node * 4) = make_float4(s0, s1, s2, s3);
}

// ---------------- MFMA bf16 GEMM (generic, BK=32 — round-7 proven config) ----------------
enum { MF_BIAS = 1, MF_LRELU = 2, MF_DINV = 4, MF_STOREF = 8, MF_STOREB = 16,
       MF_STATS = 32, MF_COLSUM = 64 };

template <int BN, int MODE>
__launch_bounds__(256)
__global__ void k_mgemm(const unsigned short* __restrict__ A, int lda, int K,
                        const unsigned short* __restrict__ W,  // [C][K]
                        const float* __restrict__ bias,
                        float* __restrict__ OutF, unsigned short* __restrict__ OutB, int ldo,
                        const float* __restrict__ dinv,
                        float* __restrict__ sum_o, float* __restrict__ ss_o,
                        unsigned* __restrict__ maxk_o) {
    constexpr int BM = 128;
    constexpr int LDT = 40;
    __shared__ unsigned short As[BM * LDT];
    __shared__ unsigned short Ws[BN * LDT];
    __shared__ float redS[2 * 128];
    __shared__ unsigned redM[128];

    const int tid = threadIdx.x;
    const int wid = tid >> 6, lane = tid & 63;
    const int quad = lane >> 4, lrow = lane & 15;
    const int bn0 = blockIdx.x * BM;
    const int bc0 = blockIdx.y * BN;

    constexpr int NI = (BN == 128) ? 4 : 2;
    constexpr int NJ = 4;
    const int wm = (BN == 128) ? (wid & 1) * 64 : wid * 32;
    const int wn = (BN == 128) ? (wid >> 1) * 64 : 0;

    if (MODE & (MF_STATS | MF_COLSUM)) {
        for (int c = tid; c < BN; c += 256) {
            redS[c] = 0.f; redS[128 + c] = 0.f; redM[c] = 0u;
        }
    }

    f32x4 acc[NI][NJ] = {};

    for (int k0 = 0; k0 < K; k0 += 32) {
#pragma unroll
        for (int h = 0; h < 2; ++h) {
            int ch = tid + h * 256;
            int row = ch >> 2, cp = ch & 3;
            const unsigned short* src = A + (size_t)(bn0 + row) * lda + k0 + cp * 8;
            *(float4*)&As[row * LDT + cp * 8] = *(const float4*)src;
        }
#pragma unroll
        for (int h = 0; h < BN / 64; ++h) {
            int ch = tid + h * 256;
            int row = ch >> 2, cp = ch & 3;
            const unsigned short* src = W + (size_t)(bc0 + row) * K + k0 + cp * 8;
            *(float4*)&Ws[row * LDT + cp * 8] = *(const float4*)src;
        }
        __syncthreads();
        frag8 af[NI], bf[NJ];
#pragma unroll
        for (int i = 0; i < NI; ++i)
            af[i] = *(const frag8*)&As[(wm + i * 16 + lrow) * LDT + quad * 8];
#pragma unroll
        for (int j = 0; j < NJ; ++j)
            bf[j] = *(const frag8*)&Ws[(wn + j * 16 + lrow) * LDT + quad * 8];
#pragma unroll
        for (int i = 0; i < NI; ++i)
#pragma unroll
            for (int j = 0; j < NJ; ++j)
                acc[i][j] = __builtin_amdgcn_mfma_f32_16x16x32_bf16(af[i], bf[j], acc[i][j], 0, 0, 0);
        __syncthreads();
    }

#pragma unroll
    for (int j = 0; j < NJ; ++j) {
        const int col = bc0 + wn + j * 16 + lrow;
        float bv = (MODE & MF_BIAS) ? bias[col] : 0.f;
        float s = 0.f, q = 0.f, m = -3.4e38f;
#pragma unroll
        for (int i = 0; i < NI; ++i) {
            const int rowb = bn0 + wm + i * 16 + quad * 4;
#pragma unroll
            for (int r = 0; r < 4; ++r) {
                float t = acc[i][j][r] + bv;
                if (MODE & MF_LRELU) t = lrelu01(t);
                if (MODE & MF_DINV) t *= dinv[rowb + r];
                if (MODE & MF_STOREF) OutF[(size_t)(rowb + r) * ldo + col] = t;
                if (MODE & MF_STOREB) OutB[(size_t)(rowb + r) * ldo + col] = f2b(t);
                s += t; q += t * t; m = fmaxf(m, t);
            }
        }
        if (MODE & (MF_STATS | MF_COLSUM)) {
            s += __shfl_xor(s, 16); s += __shfl_xor(s, 32);
            if (MODE & MF_STATS) {
                q += __shfl_xor(q, 16); q += __shfl_xor(q, 32);
                m = fmaxf(m, __shfl_xor(m, 16)); m = fmaxf(m, __shfl_xor(m, 32));
            }
            if (quad == 0) {
                int lc = wn + j * 16 + lrow;
                atomicAdd(&redS[lc], s);
                if (MODE & MF_STATS) {
                    atomicAdd(&redS[128 + lc], q);
                    atomicMax(&redM[lc], fkey(m));
                }
            }
        }
    }
    if (MODE & (MF_STATS | MF_COLSUM)) {
        __syncthreads();
        for (int c = tid; c < BN; c += 256) {
            atomAddF(&sum_o[bc0 + c], redS[c]);
            if (MODE & MF_STATS) {
                atomAddF(&ss_o[bc0 + c], redS[128 + c]);
                atomicMax(&maxk_o[bc0 + c], redM[c]);
            }
        }
    }
}

// ---------------- fused li+gc ----------------
template <int BN>
__launch_bounds__(256)
__global__ void k_ligc(const unsigned short* __restrict__ A, int lda, int K,
                       const unsigned short* __restrict__ Wli, const float* __restrict__ bli,
                       const unsigned short* __restrict__ Wgc, const float* __restrict__ dinv,
                       unsigned short* __restrict__ NF, int ldnf,
                       unsigned short* __restrict__ Q, int ldq) {
    constexpr int BM = 128;
    constexpr int LDT = 40;
    constexpr int LDT2 = BN + 8;
    __shared__ unsigned short SA[BM * LDT2];
    __shared__ unsigned short Ws[BN * LDT];

    const int tid = threadIdx.x;
    const int wid = tid >> 6, lane = tid & 63;
    const int quad = lane >> 4, lrow = lane & 15;
    const int bn0 = blockIdx.x * BM;
    constexpr int NI = (BN == 128) ? 4 : 2;
    constexpr int NJ = 4;
    const int wm = (BN == 128) ? (wid & 1) * 64 : wid * 32;
    const int wn = (BN == 128) ? (wid >> 1) * 64 : 0;

    {
        f32x4 acc[NI][NJ] = {};
        for (int k0 = 0; k0 < K; k0 += 32) {
#pragma unroll
            for (int h = 0; h < 2; ++h) {
                int ch = tid + h * 256;
                int row = ch >> 2, cp = ch & 3;
                *(float4*)&SA[row * LDT + cp * 8] =
                    *(const float4*)(A + (size_t)(bn0 + row) * lda + k0 + cp * 8);
            }
#pragma unroll
            for (int h = 0; h < BN / 64; ++h) {
                int ch = tid + h * 256;
                int row = ch >> 2, cp = ch & 3;
                *(float4*)&Ws[row * LDT + cp * 8] =
                    *(const float4*)(Wli + (size_t)row * K + k0 + cp * 8);
            }
            __syncthreads();
            frag8 af[NI], bf[NJ];
#pragma unroll
            for (int i = 0; i < NI; ++i)
                af[i] = *(const frag8*)&SA[(wm + i * 16 + lrow) * LDT + quad * 8];
#pragma unroll
            for (int j = 0; j < NJ; ++j)
                bf[j] = *(const frag8*)&Ws[(wn + j * 16 + lrow) * LDT + quad * 8];
#pragma unroll
            for (int i = 0; i < NI; ++i)
#pragma unroll
                for (int j = 0; j < NJ; ++j)
                    acc[i][j] = __builtin_amdgcn_mfma_f32_16x16x32_bf16(af[i], bf[j], acc[i][j], 0, 0, 0);
            __syncthreads();
        }
#pragma unroll
        for (int j = 0; j < NJ; ++j) {
            const int col = wn + j * 16 + lrow;
            float bv = bli[col];
#pragma unroll
            for (int i = 0; i < NI; ++i) {
                const int rowl = wm + i * 16 + quad * 4;
#pragma unroll
                for (int r = 0; r < 4; ++r) {
                    unsigned short h = f2b(lrelu01(acc[i][j][r] + bv));
                    NF[(size_t)(bn0 + rowl + r) * ldnf + col] = h;
                    SA[(rowl + r) * LDT2 + col] = h;
                }
            }
        }
        __syncthreads();
    }
    {
        f32x4 acc[NI][NJ] = {};
        for (int k0 = 0; k0 < BN; k0 += 32) {
#pragma unroll
            for (int h = 0; h < BN / 64; ++h) {
                int ch = tid + h * 256;
                int row = ch >> 2, cp = ch & 3;
                *(float4*)&Ws[row * LDT + cp * 8] =
                    *(const float4*)(Wgc + (size_t)row * BN + k0 + cp * 8);
            }
            __syncthreads();
            frag8 af[NI], bf[NJ];
#pragma unroll
            for (int i = 0; i < NI; ++i)
                af[i] = *(const frag8*)&SA[(wm + i * 16 + lrow) * LDT2 + k0 + quad * 8];
#pragma unroll
            for (int j = 0; j < NJ; ++j)
                bf[j] = *(const frag8*)&Ws[(wn + j * 16 + lrow) * LDT + quad * 8];
#pragma unroll
            for (int i = 0; i < NI; ++i)
#pragma unroll
                for (int j = 0; j < NJ; ++j)
                    acc[i][j] = __builtin_amdgcn_mfma_f32_16x16x32_bf16(af[i], bf[j], acc[i][j], 0, 0, 0);
            __syncthreads();
        }
#pragma unroll
        for (int j = 0; j < NJ; ++j) {
            const int col = wn + j * 16 + lrow;
#pragma unroll
            for (int i = 0; i < NI; ++i) {
                const int rowb = bn0 + wm + i * 16 + quad * 4;
#pragma unroll
                for (int r = 0; r < 4; ++r) {
                    float t = acc[i][j][r] * dinv[rowb + r];
                    Q[(size_t)(rowb + r) * ldq + col] = f2b(t);
                }
            }
        }
    }
}

// ---------------- z3 stats GEMM v3: fragment-order LDS, 2D grid, no K-loop ----------------
// grid (8 channel-blocks, 625 node-tiles). A tile 128x128 bf16 + W tile 128x128 bf16,
// both stored in MFMA fragment order: chunk flat=(r16*4+kc)*64+lane at byte flat*16.
// Staging writes and fragment reads are both lane-contiguous -> conflict-free.
// 64 MFMA per wave between exactly 2 barriers; shfl + global-atomic stats epilogue.
__launch_bounds__(256)
__global__ void k_z3(const unsigned short* __restrict__ A,   // [N,128] bf16 (A3)
                     const unsigned short* __restrict__ W,   // [1024,128] bf16
                     const float* __restrict__ bias,         // [1024]
                     float* __restrict__ sum_o, float* __restrict__ ss_o,
                     unsigned* __restrict__ maxk_o) {
    __shared__ unsigned short As[128 * 128];  // 32 KB
    __shared__ unsigned short Ws[128 * 128];  // 32 KB
    const int tid = threadIdx.x;
    const int wid = tid >> 6, lane = tid & 63;
    const int quad = lane >> 4, lrow = lane & 15;
    const int bn0 = blockIdx.y * 128;
    const int bc0 = blockIdx.x * 128;

#pragma unroll
    for (int h = 0; h < 8; ++h) {
        int flat = h * 256 + tid;
        int l = flat & 63, kc = (flat >> 6) & 3, r16 = flat >> 8;
        int row = r16 * 16 + (l & 15), k0 = kc * 32 + (l >> 4) * 8;
        *(float4*)&As[flat * 8] = *(const float4*)(A + (size_t)(bn0 + row) * 128 + k0);
        *(float4*)&Ws[flat * 8] = *(const float4*)(W + (size_t)(bc0 + row) * 128 + k0);
    }
    __syncthreads();

    const int ar = (wid & 1) * 4;   // A row-subtile base (16-row units)
    const int wc = (wid >> 1) * 4;  // W col-subtile base
    f32x4 acc[4][4] = {};
#pragma unroll
    for (int kc = 0; kc < 4; ++kc) {
        frag8 af[4], bf[4];
#pragma unroll
        for (int i = 0; i < 4; ++i)
            af[i] = *(const frag8*)&As[(((ar + i) * 4 + kc) * 64 + lane) * 8];
#pragma unroll
        for (int j = 0; j < 4; ++j)
            bf[j] = *(const frag8*)&Ws[(((wc + j) * 4 + kc) * 64 + lane) * 8];
#pragma unroll
        for (int i = 0; i < 4; ++i)
#pragma unroll
            for (int j = 0; j < 4; ++j)
                acc[i][j] = __builtin_amdgcn_mfma_f32_16x16x32_bf16(af[i], bf[j], acc[i][j], 0, 0, 0);
    }

    // stats epilogue: per-column sum/ss/max over this block's 128 rows
#pragma unroll
    for (int j = 0; j < 4; ++j) {
        int c = bc0 + (wc + j) * 16 + lrow;
        float bv = bias[c];
        float s = 0.f, q = 0.f, m = -3.4e38f;
#pragma unroll
        for (int i = 0; i < 4; ++i)
#pragma unroll
            for (int r = 0; r < 4; ++r) {
                float t = acc[i][j][r] + bv;
                s += t; q += t * t; m = fmaxf(m, t);
            }
        s += __shfl_xor(s, 16); s += __shfl_xor(s, 32);
        q += __shfl_xor(q, 16); q += __shfl_xor(q, 32);
        m = fmaxf(m, __shfl_xor(m, 16)); m = fmaxf(m, __shfl_xor(m, 32));
        if (quad == 0) {
            atomAddF(&sum_o[c], s);
            atomAddF(&ss_o[c], q);
            atomicMax(&maxk_o[c], fkey(m));
        }
    }
}

// ---------------- launch ----------------
// Buffer lifetimes:
//   F1 [N,128]f32: z2 only
//   B1 [N,64] u16: h1 -> nf1
//   B2 [N,128]u16: A3 -> q1 (first N*64) -> hmid -> q2 (in-place over hmid)
//   B3 [N,128]u16: hln1 -> nf2
//   H  [N,320]u16: xg cols 256.. (early), LN2 out cols 0..255 (late)

extern "C" void kernel_launch(void* const* d_in, const int* in_sizes, int n_in,
                              void* d_out, int out_size, void* d_ws, size_t ws_size,
                              hipStream_t stream) {
    const float* x   = (const float*)d_in[0];
    const int*   ei  = (const int*)d_in[1];
    const float* c1w = (const float*)d_in[2];  const float* c1b = (const float*)d_in[3];
    const float* c2w = (const float*)d_in[4];  const float* c2b = (const float*)d_in[5];
    const float* c3w = (const float*)d_in[6];  const float* c3b = (const float*)d_in[7];
    const float* f1w = (const float*)d_in[8];  const float* f1b = (const float*)d_in[9];
    const float* f2w = (const float*)d_in[10]; const float* f2b = (const float*)d_in[11];
    const float* f3w = (const float*)d_in[12]; const float* f3b = (const float*)d_in[13];
    const float* cv1w = (const float*)d_in[14]; const float* cv1b = (const float*)d_in[15];
    const float* li1w = (const float*)d_in[16]; const float* li1b = (const float*)d_in[17];
    const float* gc1w = (const float*)d_in[18]; const float* gc1b = (const float*)d_in[19];
    const float* ln1g = (const float*)d_in[20]; const float* ln1b = (const float*)d_in[21];
    const float* cv2w = (const float*)d_in[22]; const float* cv2b = (const float*)d_in[23];
    const float* li2w = (const float*)d_in[24]; const float* li2b = (const float*)d_in[25];
    const float* gc2w = (const float*)d_in[26]; const float* gc2b = (const float*)d_in[27];
    const float* ln2g = (const float*)d_in[28]; const float* ln2b = (const float*)d_in[29];
    const float* cv3w = (const float*)d_in[30]; const float* cv3b = (const float*)d_in[31];
    const float* ow  = (const float*)d_in[32]; const float* ob  = (const float*)d_in[33];
    float* out = (float*)d_out;

    const int N = in_sizes[0] / 3;
    const int E = in_sizes[1] / 2;
    const int* srcI = ei;
    const int* dstI = ei + E;

    char* base = (char*)d_ws;
    size_t off = 0;
    auto take = [&](size_t bytes) -> char* {
        char* p = base + off;
        off = (off + bytes + 255) & ~(size_t)255;
        return p;
    };
    int*   deg    = (int*)  take((size_t)N * 4);
    float* dinv   = (float*)take((size_t)N * 4);
    int*   startv = (int*)  take((size_t)N * 4);
    int*   rank   = (int*)  take((size_t)E * 4);
    int*   csr    = (int*)  take((size_t)E * 4);
    int*   bsum   = (int*)  take(512 * 4);
    float* sm     = (float*)take(8192 * 4);
    unsigned short* WB = (unsigned short*)take(278528 * 2);
    unsigned short* H  = (unsigned short*)take((size_t)N * 320 * 2);
    float* F1 = (float*)take((size_t)N * 128 * 4);
    unsigned short* B1 = (unsigned short*)take((size_t)N * 64 * 2);
    unsigned short* B2 = (unsigned short*)take((size_t)N * 128 * 2);
    unsigned short* B3 = (unsigned short*)take((size_t)N * 128 * 2);

    unsigned short* c2wb  = WB + 0;
    unsigned short* c3wb  = WB + 8192;
    unsigned short* li1wb = WB + 139264;
    unsigned short* gc1wb = WB + 143360;
    unsigned short* cv2wb = WB + 147456;
    unsigned short* li2wb = WB + 163840;
    unsigned short* gc2wb = WB + 180224;
    unsigned short* cv3wb = WB + 196608;

    float* sum2 = sm + 0;    float* ss2 = sm + 128;
    float* sum3 = sm + 256;  float* ss3 = sm + 1280;
    unsigned* maxk = (unsigned*)(sm + 2304);
    float* pooled = sm + 3328;
    unsigned* dmax = (unsigned*)(sm + 3584);
    float* mu2 = sm + 3712; float* rs2 = sm + 3840;
    float* T9  = sm + 3968; float* c4 = sm + 3984;
    float* gbuf = sm + 4096;
    float* a1   = sm + 5120;

    const float invn = 1.0f / (float)N;
    const dim3 blk(256);
    const unsigned GX = (unsigned)(N / 128);
    const unsigned NB = cdivu((unsigned)N, 256);

    hipMemsetAsync(deg, 0, (size_t)N * 4, stream);
    hipMemsetAsync(sm, 0, 3712 * 4, stream);

    // ---- graph prep ----
    k_degrank<<<cdivu(E, 256), blk, 0, stream>>>(dstI, deg, rank, E);
    k_dinv<<<cdivu(N, 256), blk, 0, stream>>>(deg, dinv, N);
    k_scan_local<<<NB, blk, 0, stream>>>(deg, startv, bsum, N);
    k_scan_bsum<<<1, 512, 0, stream>>>(bsum, (int)NB);
    k_scan_add<<<NB, blk, 0, stream>>>(startv, bsum, N);
    k_fill<<<cdivu(E, 256), blk, 0, stream>>>(srcI, dstI, rank, startv, csr, E);

    k_wconv<<<cdivu(278528, 256), blk, 0, stream>>>(c2w, c3w, li1w, gc1w, cv2w, li2w, gc2w, cv3w, WB);

    // ---- TNet ----
    k_h1<<<cdivu((unsigned)N, 256), blk, 0, stream>>>(x, c1w, c1b, B1, N);
    k_mgemm<128, (MF_BIAS | MF_STOREF | MF_STATS)><<<dim3(GX, 1), blk, 0, stream>>>(
        B1, 64, 64, c2wb, c2b, F1, nullptr, 128, nullptr, sum2, ss2, dmax);
    k_murs<<<1, 128, 0, stream>>>(sum2, ss2, mu2, rs2, invn);
    k_prebn<<<cdivu((unsigned)N * 128 / 4, 256), blk, 0, stream>>>(F1, mu2, rs2, B2, N * 128);
    k_z3<<<dim3(8, GX), blk, 0, stream>>>(B2, c3wb, c3b, sum3, ss3, maxk);
    k_g<<<4, blk, 0, stream>>>(sum3, ss3, maxk, gbuf, invn);
    k_fc1<<<8, blk, 0, stream>>>(gbuf, f1w, f1b, a1);
    k_fc23<<<1, blk, 0, stream>>>(a1, f2w, f2b, f3w, f3b, T9);
    k_xg<<<cdivu((unsigned)N, 256), blk, 0, stream>>>(x, T9, cv1w, cv1b, H + 256, N);

    // ---- GCN block 1 (C=64) ----
    k_ligc<64><<<GX, blk, 0, stream>>>(H + 256, 320, 64, li1wb, li1b, gc1wb, dinv, B1, 64, B2, 64);
    k_gln<64><<<cdivu((unsigned)N, 4), blk, 0, stream>>>(
        startv, deg, csr, B2, B1, dinv, gc1b, ln1g, ln1b, B3, 128, N);
    k_mgemm<128, (MF_BIAS | MF_LRELU | MF_STOREB)><<<dim3(GX, 1), blk, 0, stream>>>(
        B3, 128, 128, cv2wb, cv2b, nullptr, B2, 128, nullptr, nullptr, nullptr, nullptr);

    // ---- GCN block 2 (C=128) ----
    k_ligc<128><<<GX, blk, 0, stream>>>(B2, 128, 128, li2wb, li2b, gc2wb, dinv, B3, 128, B2, 128);
    k_gln<128><<<cdivu((unsigned)N, 4), blk, 0, stream>>>(
        startv, deg, csr, B2, B3, dinv, gc2b, ln2g, ln2b, H, 320, N);

    // ---- conv3 (K=320 -> 256) fused column-sum only ----
    k_mgemm<128, (MF_BIAS | MF_LRELU | MF_COLSUM)><<<dim3(GX, 2), blk, 0, stream>>>(
        H, 320, 320, cv3wb, cv3b, nullptr, nullptr, 0, nullptr, pooled, nullptr, nullptr);

    // ---- head ----
    k_const4<<<1, 256, 0, stream>>>(pooled, ow, ob, c4, invn);
    k_out<<<cdivu((unsigned)N, 256), blk, 0, stream>>>(H, ow, c4, out, N);
}

// Round 10
// 565.690 us; speedup vs baseline: 1.0757x; 1.0172x over previous
//
#include <hip/hip_runtime.h>
#include <cstddef>

#define EPSV 1e-5f

typedef __attribute__((ext_vector_type(8))) short frag8;   // 8 bf16 (4 VGPRs)
typedef __attribute__((ext_vector_type(4))) float f32x4;   // MFMA acc

__device__ __forceinline__ float lrelu01(float v) { return v > 0.f ? v : 0.01f * v; }
__device__ __forceinline__ void atomAddF(float* p, float v) { unsafeAtomicAdd(p, v); }
__device__ __forceinline__ unsigned fkey(float f) {
    unsigned u = __float_as_uint(f);
    return (u & 0x80000000u) ? ~u : (u | 0x80000000u);
}
__device__ __forceinline__ unsigned short f2b(float f) {  // RNE float->bf16
    unsigned u = __float_as_uint(f);
    unsigned r = u + 0x7fffu + ((u >> 16) & 1u);
    return (unsigned short)(r >> 16);
}
__device__ __forceinline__ float b2f(unsigned short h) {
    return __uint_as_float(((unsigned)h) << 16);
}
__device__ __forceinline__ float blo(unsigned u) { return __uint_as_float(u << 16); }
__device__ __forceinline__ float bhi(unsigned u) { return __uint_as_float(u & 0xffff0000u); }

static inline unsigned cdivu(unsigned a, unsigned b) { return (a + b - 1) / b; }

// ---------------- graph prep: degree+rank, dinv, CSR build ----------------

__global__ void k_degrank(const int* __restrict__ dst, int* __restrict__ deg,
                          int* __restrict__ rank, int E) {
    int e = blockIdx.x * 256 + threadIdx.x;
    if (e < E) rank[e] = atomicAdd(&deg[dst[e]], 1);
}

// scan of deg -> startv (local) + block sums; fused dinv = rsqrt(deg+1)
__global__ void k_scan_local(const int* __restrict__ deg, int* __restrict__ startv,
                             int* __restrict__ bsum, float* __restrict__ dinv, int n) {
    __shared__ int t0[256];
    int tid = threadIdx.x;
    int i = blockIdx.x * 256 + tid;
    int v = (i < n) ? deg[i] : 0;
    if (i < n) dinv[i] = rsqrtf((float)(v + 1));  // +1 self loop
    t0[tid] = v;
    __syncthreads();
    for (int o = 1; o < 256; o <<= 1) {
        int add = (tid >= o) ? t0[tid - o] : 0;
        __syncthreads();
        t0[tid] += add;
        __syncthreads();
    }
    if (i < n) startv[i] = t0[tid] - v;
    if (tid == 255) bsum[blockIdx.x] = t0[255];
}

__global__ void k_scan_bsum(int* __restrict__ bsum, int nb) {
    __shared__ int t0[512];
    int tid = threadIdx.x;
    int v = (tid < nb) ? bsum[tid] : 0;
    t0[tid] = v;
    __syncthreads();
    for (int o = 1; o < 512; o <<= 1) {
        int add = (tid >= o) ? t0[tid - o] : 0;
        __syncthreads();
        t0[tid] += add;
        __syncthreads();
    }
    if (tid < nb) bsum[tid] = t0[tid] - v;
}

__global__ void k_scan_add(int* __restrict__ startv, const int* __restrict__ bsum, int n) {
    int i = blockIdx.x * 256 + threadIdx.x;
    if (i < n) startv[i] += bsum[blockIdx.x];
}

__global__ void k_fill(const int* __restrict__ src, const int* __restrict__ dst,
                       const int* __restrict__ rank, const int* __restrict__ startv,
                       int* __restrict__ csr, int E) {
    int e = blockIdx.x * 256 + threadIdx.x;
    if (e < E) csr[startv[dst[e]] + rank[e]] = src[e];
}

// ---------------- fused gather + LN (16-lane groups, dwordx4 rows) ----------------
template <int CH>
__launch_bounds__(256)
__global__ void k_gln(const int* __restrict__ startv, const int* __restrict__ degv,
                      const int* __restrict__ csr, const unsigned short* __restrict__ q,
                      const unsigned short* __restrict__ nf, const float* __restrict__ dinv,
                      const float* __restrict__ gcn_b, const float* __restrict__ lng,
                      const float* __restrict__ lnb, unsigned short* __restrict__ outp,
                      int ldo, int n) {
    const int wv = threadIdx.x >> 6, lane = threadIdx.x & 63;
    const int g = lane >> 4, p = lane & 15;
    int node = blockIdx.x * 4 + wv;
    if (node >= n) return;
    constexpr int CPL = CH / 16;   // channels per lane
    constexpr int DPL = CPL / 2;   // dwords per lane per row

    float acc[CPL];
#pragma unroll
    for (int k = 0; k < CPL; ++k) acc[k] = 0.f;

    {
        unsigned su[DPL];
        const unsigned short* qrow = q + (size_t)node * CH + p * CPL;
        if (DPL == 4) *(uint4*)su = *(const uint4*)qrow;
        else          *(uint2*)su = *(const uint2*)qrow;
        if (g == 0) {
#pragma unroll
            for (int d = 0; d < DPL; ++d) { acc[2 * d] += blo(su[d]); acc[2 * d + 1] += bhi(su[d]); }
        }
    }

    int s0 = startv[node], cnt = degv[node];
    int sidx[4];
#pragma unroll
    for (int t = 0; t < 4; ++t) { int j = t * 4 + g; sidx[t] = (j < cnt) ? csr[s0 + j] : 0; }
    for (int j0 = 0; j0 < cnt; j0 += 16) {
        unsigned buf[4][DPL];
#pragma unroll
        for (int t = 0; t < 4; ++t) {
            const unsigned short* src = q + (size_t)sidx[t] * CH + p * CPL;
            if (DPL == 4) *(uint4*)buf[t] = *(const uint4*)src;
            else          *(uint2*)buf[t] = *(const uint2*)src;
        }
        int nsidx[4];
#pragma unroll
        for (int t = 0; t < 4; ++t) {
            int j = j0 + 16 + t * 4 + g;
            nsidx[t] = (j < cnt) ? csr[s0 + j] : 0;
        }
#pragma unroll
        for (int t = 0; t < 4; ++t) {
            if (j0 + t * 4 + g < cnt) {
#pragma unroll
                for (int d = 0; d < DPL; ++d) {
                    acc[2 * d] += blo(buf[t][d]);
                    acc[2 * d + 1] += bhi(buf[t][d]);
                }
            }
        }
#pragma unroll
        for (int t = 0; t < 4; ++t) sidx[t] = nsidx[t];
    }

#pragma unroll
    for (int k = 0; k < CPL; ++k) {
        acc[k] += __shfl_xor(acc[k], 16);
        acc[k] += __shfl_xor(acc[k], 32);
    }

    float di = dinv[node];
    float nv[CPL], bv[CPL];
    {
        unsigned su[DPL];
        const unsigned short* nrow = nf + (size_t)node * CH + p * CPL;
        if (DPL == 4) *(uint4*)su = *(const uint4*)nrow;
        else          *(uint2*)su = *(const uint2*)nrow;
#pragma unroll
        for (int d = 0; d < DPL; ++d) { nv[2 * d] = blo(su[d]); nv[2 * d + 1] = bhi(su[d]); }
    }
    const float* gb = gcn_b + p * CPL;
#pragma unroll
    for (int k = 0; k < CPL; ++k) bv[k] = lrelu01(di * acc[k] + gb[k]);

    float s = 0.f, ss = 0.f;
#pragma unroll
    for (int k = 0; k < CPL; ++k) { s += nv[k] + bv[k]; ss += nv[k] * nv[k] + bv[k] * bv[k]; }
#pragma unroll
    for (int off = 32; off > 0; off >>= 1) { s += __shfl_xor(s, off); ss += __shfl_xor(ss, off); }
    const float inv = 1.f / (float)(8 * CH);  // 4x group replication * 2*CH channels
    float mu = s * inv;
    float var = ss * inv - mu * mu;
    float rsg = rsqrtf(var + EPSV);

    unsigned short* orow = outp + (size_t)node * ldo;
    if (g == 0) {
        unsigned short tmp[CPL];
        const float* lg = lng + p * CPL; const float* lb = lnb + p * CPL;
#pragma unroll
        for (int k = 0; k < CPL; ++k) tmp[k] = f2b((nv[k] - mu) * rsg * lg[k] + lb[k]);
        if (DPL == 4) *(uint4*)(orow + p * CPL) = *(uint4*)tmp;
        else          *(uint2*)(orow + p * CPL) = *(uint2*)tmp;
    } else if (g == 1) {
        unsigned short tmp[CPL];
        const float* lg = lng + CH + p * CPL; const float* lb = lnb + CH + p * CPL;
#pragma unroll
        for (int k = 0; k < CPL; ++k) tmp[k] = f2b((bv[k] - mu) * rsg * lg[k] + lb[k]);
        if (DPL == 4) *(uint4*)(orow + CH + p * CPL) = *(uint4*)tmp;
        else          *(uint2*)(orow + CH + p * CPL) = *(uint2*)tmp;
    }
}

// ---------------- small kernels ----------------

__global__ void k_wconv(const float* __restrict__ s0, const float* __restrict__ s1,
                        const float* __restrict__ s2, const float* __restrict__ s3,
                        const float* __restrict__ s4, const float* __restrict__ s5,
                        const float* __restrict__ s6, const float* __restrict__ s7,
                        unsigned short* __restrict__ dst) {
    int t = blockIdx.x * 256 + threadIdx.x;
    if (t >= 278528) return;
    const float* srcs[8] = {s0, s1, s2, s3, s4, s5, s6, s7};
    const int off[9] = {0, 8192, 139264, 143360, 147456, 163840, 180224, 196608, 278528};
    int seg = 0;
    while (t >= off[seg + 1]) ++seg;
    dst[t] = f2b(srcs[seg][t - off[seg]]);
}

__global__ void k_h1(const float* __restrict__ x, const float* __restrict__ w,
                     const float* __restrict__ b, unsigned short* __restrict__ h1, int n) {
    int node = blockIdx.x * 256 + threadIdx.x;
    if (node >= n) return;
    float x0 = x[node * 3], x1 = x[node * 3 + 1], x2 = x[node * 3 + 2];
    unsigned short* o = h1 + (size_t)node * 64;
#pragma unroll
    for (int cp = 0; cp < 8; ++cp) {
        unsigned short tmp[8];
#pragma unroll
        for (int t = 0; t < 8; ++t) {
            int c = cp * 8 + t;
            float v = x0 * w[c * 3] + x1 * w[c * 3 + 1] + x2 * w[c * 3 + 2] + b[c];
            tmp[t] = f2b(fmaxf(v, 0.f));
        }
        *(float4*)(o + cp * 8) = *(float4*)tmp;
    }
}

// A3 = bf16(relu((z2 - mu)*rs)) with mu/rs computed inline from sum2/ss2
__global__ void k_prebn(const float* __restrict__ z, const float* __restrict__ sum2,
                        const float* __restrict__ ss2, unsigned short* __restrict__ a3,
                        int total, float invn) {
    int t = (blockIdx.x * 256 + threadIdx.x) * 4;
    if (t >= total) return;
    int c = t & 127;
    float4 v = *(const float4*)(z + t);
    float vv[4] = {v.x, v.y, v.z, v.w};
    unsigned short o[4];
#pragma unroll
    for (int i = 0; i < 4; ++i) {
        float m = sum2[c + i] * invn;
        float var = ss2[c + i] * invn - m * m;
        o[i] = f2b(fmaxf((vv[i] - m) * rsqrtf(var + EPSV), 0.f));
    }
    *(ushort4*)(a3 + t) = *(ushort4*)o;
}

// fc1 with fused g-compute: g[c]=relu((max-mu)*rsqrt(var+eps)) built in LDS per block
__launch_bounds__(256)
__global__ void k_fc1(const float* __restrict__ sum3, const float* __restrict__ ss3,
                      const unsigned* __restrict__ maxk,
                      const float* __restrict__ f1w, const float* __restrict__ f1b,
                      float* __restrict__ a1, float invn) {
    __shared__ float g[1024];
    int tid = threadIdx.x;
    for (int c = tid; c < 1024; c += 256) {
        float m = sum3[c] * invn;
        float var = ss3[c] * invn - m * m;
        unsigned k = maxk[c];
        unsigned u = (k & 0x80000000u) ? (k & 0x7FFFFFFFu) : ~k;
        g[c] = fmaxf((__uint_as_float(u) - m) * rsqrtf(var + EPSV), 0.f);
    }
    __syncthreads();
    int row = blockIdx.x * 64 + (tid >> 2);
    int part = tid & 3;
    const float* w = f1w + (size_t)row * 1024 + part * 256;
    const float* gg = g + part * 256;
    float s = 0.f;
    for (int k = 0; k < 256; ++k) s = fmaf(w[k], gg[k], s);
    s += __shfl_xor(s, 1); s += __shfl_xor(s, 2);
    if (part == 0) a1[row] = fmaxf(s + f1b[row], 0.f);
}

__launch_bounds__(256)
__global__ void k_fc23(const float* __restrict__ a1, const float* __restrict__ f2w,
                       const float* __restrict__ f2b, const float* __restrict__ f3w,
                       const float* __restrict__ f3b, float* __restrict__ T9) {
    __shared__ float a2[256];
    int tid = threadIdx.x;
    {
        const float* w = f2w + (size_t)tid * 512;
        float s = f2b[tid];
        for (int k = 0; k < 512; ++k) s = fmaf(w[k], a1[k], s);
        a2[tid] = fmaxf(s, 0.f);
    }
    __syncthreads();
    if (tid < 9) {
        const float* w = f3w + (size_t)tid * 256;
        float s = f3b[tid];
        for (int k = 0; k < 256; ++k) s = fmaf(w[k], a2[k], s);
        if (tid == 0 || tid == 4 || tid == 8) s += 1.f;
        T9[tid] = s;
    }
}

__global__ void k_xg(const float* __restrict__ x, const float* __restrict__ T9,
                     const float* __restrict__ w, const float* __restrict__ b,
                     unsigned short* __restrict__ xg, int n) {
    int node = blockIdx.x * 256 + threadIdx.x;
    if (node >= n) return;
    float x0 = x[node * 3], x1 = x[node * 3 + 1], x2 = x[node * 3 + 2];
    float h0 = x0 * T9[0] + x1 * T9[3] + x2 * T9[6];
    float h1 = x0 * T9[1] + x1 * T9[4] + x2 * T9[7];
    float h2 = x0 * T9[2] + x1 * T9[5] + x2 * T9[8];
    unsigned short* o = xg + (size_t)node * 320;
#pragma unroll
    for (int cp = 0; cp < 8; ++cp) {
        unsigned short tmp[8];
#pragma unroll
        for (int t = 0; t < 8; ++t) {
            int c = cp * 8 + t;
            float v = h0 * w[c * 3] + h1 * w[c * 3 + 1] + h2 * w[c * 3 + 2] + b[c];
            tmp[t] = f2b(lrelu01(v));
        }
        *(float4*)(o + cp * 8) = *(float4*)tmp;
    }
}

__global__ void k_const4(const float* __restrict__ pooled, const float* __restrict__ ow,
                         const float* __restrict__ ob, float* __restrict__ c4, float invn) {
    int j = threadIdx.x >> 6, lane = threadIdx.x & 63;
    float s = 0.f;
    for (int c = lane; c < 256; c += 64) s += pooled[c] * invn * ow[j * 320 + c];
#pragma unroll
    for (int off = 32; off > 0; off >>= 1) s += __shfl_down(s, off);
    if (lane == 0) c4[j] = s + ob[j];
}

__global__ void k_out(const unsigned short* __restrict__ hcat, const float* __restrict__ ow,
                      const float* __restrict__ c4, float* __restrict__ out, int n) {
    int node = blockIdx.x * 256 + threadIdx.x;
    if (node >= n) return;
    const unsigned short* xgp = hcat + (size_t)node * 320 + 256;
    float s0 = c4[0], s1 = c4[1], s2 = c4[2], s3 = c4[3];
#pragma unroll
    for (int cp = 0; cp < 8; ++cp) {
        float4 raw = *(const float4*)(xgp + cp * 8);
        unsigned short tmp[8];
        *(float4*)tmp = raw;
#pragma unroll
        for (int t = 0; t < 8; ++t) {
            int k = 256 + cp * 8 + t;
            float f = b2f(tmp[t]);
            s0 = fmaf(f, ow[k], s0);
            s1 = fmaf(f, ow[320 + k], s1);
            s2 = fmaf(f, ow[640 + k], s2);
            s3 = fmaf(f, ow[960 + k], s3);
        }
    }
    *(float4*)(out + (size_t)node * 4) = make_float4(s0, s1, s2, s3);
}

// ---------------- MFMA bf16 GEMM (generic, BK=32) ----------------
enum { MF_BIAS = 1, MF_LRELU = 2, MF_DINV = 4, MF_STOREF = 8, MF_STOREB = 16,
       MF_STATS = 32, MF_COLSUM = 64 };

template <int BN, int MODE>
__launch_bounds__(256)
__global__ void k_mgemm(const unsigned short* __restrict__ A, int lda, int K,
                        const unsigned short* __restrict__ W,  // [C][K]
                        const float* __restrict__ bias,
                        float* __restrict__ OutF, unsigned short* __restrict__ OutB, int ldo,
                        const float* __restrict__ dinv,
                        float* __restrict__ sum_o, float* __restrict__ ss_o,
                        unsigned* __restrict__ maxk_o) {
    constexpr int BM = 128;
    constexpr int LDT = 40;
    __shared__ unsigned short As[BM * LDT];
    __shared__ unsigned short Ws[BN * LDT];
    __shared__ float redS[2 * 128];
    __shared__ unsigned redM[128];

    const int tid = threadIdx.x;
    const int wid = tid >> 6, lane = tid & 63;
    const int quad = lane >> 4, lrow = lane & 15;
    const int bn0 = blockIdx.x * BM;
    const int bc0 = blockIdx.y * BN;

    constexpr int NI = (BN == 128) ? 4 : 2;
    constexpr int NJ = 4;
    const int wm = (BN == 128) ? (wid & 1) * 64 : wid * 32;
    const int wn = (BN == 128) ? (wid >> 1) * 64 : 0;

    if (MODE & (MF_STATS | MF_COLSUM)) {
        for (int c = tid; c < BN; c += 256) {
            redS[c] = 0.f; redS[128 + c] = 0.f; redM[c] = 0u;
        }
    }

    f32x4 acc[NI][NJ] = {};

    for (int k0 = 0; k0 < K; k0 += 32) {
#pragma unroll
        for (int h = 0; h < 2; ++h) {
            int ch = tid + h * 256;
            int row = ch >> 2, cp = ch & 3;
            const unsigned short* src = A + (size_t)(bn0 + row) * lda + k0 + cp * 8;
            *(float4*)&As[row * LDT + cp * 8] = *(const float4*)src;
        }
#pragma unroll
        for (int h = 0; h < BN / 64; ++h) {
            int ch = tid + h * 256;
            int row = ch >> 2, cp = ch & 3;
            const unsigned short* src = W + (size_t)(bc0 + row) * K + k0 + cp * 8;
            *(float4*)&Ws[row * LDT + cp * 8] = *(const float4*)src;
        }
        __syncthreads();
        frag8 af[NI], bf[NJ];
#pragma unroll
        for (int i = 0; i < NI; ++i)
            af[i] = *(const frag8*)&As[(wm + i * 16 + lrow) * LDT + quad * 8];
#pragma unroll
        for (int j = 0; j < NJ; ++j)
            bf[j] = *(const frag8*)&Ws[(wn + j * 16 + lrow) * LDT + quad * 8];
#pragma unroll
        for (int i = 0; i < NI; ++i)
#pragma unroll
            for (int j = 0; j < NJ; ++j)
                acc[i][j] = __builtin_amdgcn_mfma_f32_16x16x32_bf16(af[i], bf[j], acc[i][j], 0, 0, 0);
        __syncthreads();
    }

#pragma unroll
    for (int j = 0; j < NJ; ++j) {
        const int col = bc0 + wn + j * 16 + lrow;
        float bv = (MODE & MF_BIAS) ? bias[col] : 0.f;
        float s = 0.f, q = 0.f, m = -3.4e38f;
#pragma unroll
        for (int i = 0; i < NI; ++i) {
            const int rowb = bn0 + wm + i * 16 + quad * 4;
#pragma unroll
            for (int r = 0; r < 4; ++r) {
                float t = acc[i][j][r] + bv;
                if (MODE & MF_LRELU) t = lrelu01(t);
                if (MODE & MF_DINV) t *= dinv[rowb + r];
                if (MODE & MF_STOREF) OutF[(size_t)(rowb + r) * ldo + col] = t;
                if (MODE & MF_STOREB) OutB[(size_t)(rowb + r) * ldo + col] = f2b(t);
                s += t; q += t * t; m = fmaxf(m, t);
            }
        }
        if (MODE & (MF_STATS | MF_COLSUM)) {
            s += __shfl_xor(s, 16); s += __shfl_xor(s, 32);
            if (MODE & MF_STATS) {
                q += __shfl_xor(q, 16); q += __shfl_xor(q, 32);
                m = fmaxf(m, __shfl_xor(m, 16)); m = fmaxf(m, __shfl_xor(m, 32));
            }
            if (quad == 0) {
                int lc = wn + j * 16 + lrow;
                atomicAdd(&redS[lc], s);
                if (MODE & MF_STATS) {
                    atomicAdd(&redS[128 + lc], q);
                    atomicMax(&redM[lc], fkey(m));
                }
            }
        }
    }
    if (MODE & (MF_STATS | MF_COLSUM)) {
        __syncthreads();
        for (int c = tid; c < BN; c += 256) {
            atomAddF(&sum_o[bc0 + c], redS[c]);
            if (MODE & MF_STATS) {
                atomAddF(&ss_o[bc0 + c], redS[128 + c]);
                atomicMax(&maxk_o[bc0 + c], redM[c]);
            }
        }
    }
}

// ---------------- fused li+gc ----------------
template <int BN>
__launch_bounds__(256)
__global__ void k_ligc(const unsigned short* __restrict__ A, int lda, int K,
                       const unsigned short* __restrict__ Wli, const float* __restrict__ bli,
                       const unsigned short* __restrict__ Wgc, const float* __restrict__ dinv,
                       unsigned short* __restrict__ NF, int ldnf,
                       unsigned short* __restrict__ Q, int ldq) {
    constexpr int BM = 128;
    constexpr int LDT = 40;
    constexpr int LDT2 = BN + 8;
    __shared__ unsigned short SA[BM * LDT2];
    __shared__ unsigned short Ws[BN * LDT];

    const int tid = threadIdx.x;
    const int wid = tid >> 6, lane = tid & 63;
    const int quad = lane >> 4, lrow = lane & 15;
    const int bn0 = blockIdx.x * BM;
    constexpr int NI = (BN == 128) ? 4 : 2;
    constexpr int NJ = 4;
    const int wm = (BN == 128) ? (wid & 1) * 64 : wid * 32;
    const int wn = (BN == 128) ? (wid >> 1) * 64 : 0;

    {
        f32x4 acc[NI][NJ] = {};
        for (int k0 = 0; k0 < K; k0 += 32) {
#pragma unroll
            for (int h = 0; h < 2; ++h) {
                int ch = tid + h * 256;
                int row = ch >> 2, cp = ch & 3;
                *(float4*)&SA[row * LDT + cp * 8] =
                    *(const float4*)(A + (size_t)(bn0 + row) * lda + k0 + cp * 8);
            }
#pragma unroll
            for (int h = 0; h < BN / 64; ++h) {
                int ch = tid + h * 256;
                int row = ch >> 2, cp = ch & 3;
                *(float4*)&Ws[row * LDT + cp * 8] =
                    *(const float4*)(Wli + (size_t)row * K + k0 + cp * 8);
            }
            __syncthreads();
            frag8 af[NI], bf[NJ];
#pragma unroll
            for (int i = 0; i < NI; ++i)
                af[i] = *(const frag8*)&SA[(wm + i * 16 + lrow) * LDT + quad * 8];
#pragma unroll
            for (int j = 0; j < NJ; ++j)
                bf[j] = *(const frag8*)&Ws[(wn + j * 16 + lrow) * LDT + quad * 8];
#pragma unroll
            for (int i = 0; i < NI; ++i)
#pragma unroll
                for (int j = 0; j < NJ; ++j)
                    acc[i][j] = __builtin_amdgcn_mfma_f32_16x16x32_bf16(af[i], bf[j], acc[i][j], 0, 0, 0);
            __syncthreads();
        }
#pragma unroll
        for (int j = 0; j < NJ; ++j) {
            const int col = wn + j * 16 + lrow;
            float bv = bli[col];
#pragma unroll
            for (int i = 0; i < NI; ++i) {
                const int rowl = wm + i * 16 + quad * 4;
#pragma unroll
                for (int r = 0; r < 4; ++r) {
                    unsigned short h = f2b(lrelu01(acc[i][j][r] + bv));
                    NF[(size_t)(bn0 + rowl + r) * ldnf + col] = h;
                    SA[(rowl + r) * LDT2 + col] = h;
                }
            }
        }
        __syncthreads();
    }
    {
        f32x4 acc[NI][NJ] = {};
        for (int k0 = 0; k0 < BN; k0 += 32) {
#pragma unroll
            for (int h = 0; h < BN / 64; ++h) {
                int ch = tid + h * 256;
                int row = ch >> 2, cp = ch & 3;
                *(float4*)&Ws[row * LDT + cp * 8] =
                    *(const float4*)(Wgc + (size_t)row * BN + k0 + cp * 8);
            }
            __syncthreads();
            frag8 af[NI], bf[NJ];
#pragma unroll
            for (int i = 0; i < NI; ++i)
                af[i] = *(const frag8*)&SA[(wm + i * 16 + lrow) * LDT2 + k0 + quad * 8];
#pragma unroll
            for (int j = 0; j < NJ; ++j)
                bf[j] = *(const frag8*)&Ws[(wn + j * 16 + lrow) * LDT + quad * 8];
#pragma unroll
            for (int i = 0; i < NI; ++i)
#pragma unroll
                for (int j = 0; j < NJ; ++j)
                    acc[i][j] = __builtin_amdgcn_mfma_f32_16x16x32_bf16(af[i], bf[j], acc[i][j], 0, 0, 0);
            __syncthreads();
        }
#pragma unroll
        for (int j = 0; j < NJ; ++j) {
            const int col = wn + j * 16 + lrow;
#pragma unroll
            for (int i = 0; i < NI; ++i) {
                const int rowb = bn0 + wm + i * 16 + quad * 4;
#pragma unroll
                for (int r = 0; r < 4; ++r) {
                    float t = acc[i][j][r] * dinv[rowb + r];
                    Q[(size_t)(rowb + r) * ldq + col] = f2b(t);
                }
            }
        }
    }
}

// ---------------- z3 stats GEMM v4: fragment-order LDS + XCD-locality swizzle ----------------
// 1D grid of 5000. bid -> (tile, cb) via transpose so XCD k (= bid%8) gets a contiguous
// ~78-tile range with ALL 8 channel-blocks: A working set ~2.5 MB fits the 4 MB per-XCD L2.
__launch_bounds__(256)
__global__ void k_z3(const unsigned short* __restrict__ A,   // [N,128] bf16 (A3)
                     const unsigned short* __restrict__ W,   // [1024,128] bf16
                     const float* __restrict__ bias,         // [1024]
                     float* __restrict__ sum_o, float* __restrict__ ss_o,
                     unsigned* __restrict__ maxk_o, int ntiles) {
    __shared__ unsigned short As[128 * 128];  // 32 KB, fragment order
    __shared__ unsigned short Ws[128 * 128];  // 32 KB, fragment order
    const int tid = threadIdx.x;
    const int wid = tid >> 6, lane = tid & 63;
    const int quad = lane >> 4, lrow = lane & 15;

    int bid = blockIdx.x;
    int w = (bid & 7) * ntiles + (bid >> 3);  // transpose: XCD = bid%8 -> contiguous tile range
    const int bn0 = (w >> 3) * 128;           // tile
    const int bc0 = (w & 7) * 128;            // channel block

#pragma unroll
    for (int h = 0; h < 8; ++h) {
        int flat = h * 256 + tid;
        int l = flat & 63, kc = (flat >> 6) & 3, r16 = flat >> 8;
        int row = r16 * 16 + (l & 15), k0 = kc * 32 + (l >> 4) * 8;
        *(float4*)&As[flat * 8] = *(const float4*)(A + (size_t)(bn0 + row) * 128 + k0);
        *(float4*)&Ws[flat * 8] = *(const float4*)(W + (size_t)(bc0 + row) * 128 + k0);
    }
    __syncthreads();

    const int ar = (wid & 1) * 4;   // A row-subtile base (16-row units)
    const int wc = (wid >> 1) * 4;  // W col-subtile base
    f32x4 acc[4][4] = {};
#pragma unroll
    for (int kc = 0; kc < 4; ++kc) {
        frag8 af[4], bf[4];
#pragma unroll
        for (int i = 0; i < 4; ++i)
            af[i] = *(const frag8*)&As[(((ar + i) * 4 + kc) * 64 + lane) * 8];
#pragma unroll
        for (int j = 0; j < 4; ++j)
            bf[j] = *(const frag8*)&Ws[(((wc + j) * 4 + kc) * 64 + lane) * 8];
#pragma unroll
        for (int i = 0; i < 4; ++i)
#pragma unroll
            for (int j = 0; j < 4; ++j)
                acc[i][j] = __builtin_amdgcn_mfma_f32_16x16x32_bf16(af[i], bf[j], acc[i][j], 0, 0, 0);
    }

#pragma unroll
    for (int j = 0; j < 4; ++j) {
        int c = bc0 + (wc + j) * 16 + lrow;
        float bv = bias[c];
        float s = 0.f, q = 0.f, m = -3.4e38f;
#pragma unroll
        for (int i = 0; i < 4; ++i)
#pragma unroll
            for (int r = 0; r < 4; ++r) {
                float t = acc[i][j][r] + bv;
                s += t; q += t * t; m = fmaxf(m, t);
            }
        s += __shfl_xor(s, 16); s += __shfl_xor(s, 32);
        q += __shfl_xor(q, 16); q += __shfl_xor(q, 32);
        m = fmaxf(m, __shfl_xor(m, 16)); m = fmaxf(m, __shfl_xor(m, 32));
        if (quad == 0) {
            atomAddF(&sum_o[c], s);
            atomAddF(&ss_o[c], q);
            atomicMax(&maxk_o[c], fkey(m));
        }
    }
}

// ---------------- launch ----------------
// Buffer lifetimes:
//   F1 [N,128]f32: z2 only
//   B1 [N,64] u16: h1 -> nf1
//   B2 [N,128]u16: A3 -> q1 (first N*64) -> hmid -> q2 (in-place over hmid)
//   B3 [N,128]u16: hln1 -> nf2
//   H  [N,320]u16: xg cols 256.. (early), LN2 out cols 0..255 (late)

extern "C" void kernel_launch(void* const* d_in, const int* in_sizes, int n_in,
                              void* d_out, int out_size, void* d_ws, size_t ws_size,
                              hipStream_t stream) {
    const float* x   = (const float*)d_in[0];
    const int*   ei  = (const int*)d_in[1];
    const float* c1w = (const float*)d_in[2];  const float* c1b = (const float*)d_in[3];
    const float* c2w = (const float*)d_in[4];  const float* c2b = (const float*)d_in[5];
    const float* c3w = (const float*)d_in[6];  const float* c3b = (const float*)d_in[7];
    const float* f1w = (const float*)d_in[8];  const float* f1b = (const float*)d_in[9];
    const float* f2w = (const float*)d_in[10]; const float* f2b = (const float*)d_in[11];
    const float* f3w = (const float*)d_in[12]; const float* f3b = (const float*)d_in[13];
    const float* cv1w = (const float*)d_in[14]; const float* cv1b = (const float*)d_in[15];
    const float* li1w = (const float*)d_in[16]; const float* li1b = (const float*)d_in[17];
    const float* gc1w = (const float*)d_in[18]; const float* gc1b = (const float*)d_in[19];
    const float* ln1g = (const float*)d_in[20]; const float* ln1b = (const float*)d_in[21];
    const float* cv2w = (const float*)d_in[22]; const float* cv2b = (const float*)d_in[23];
    const float* li2w = (const float*)d_in[24]; const float* li2b = (const float*)d_in[25];
    const float* gc2w = (const float*)d_in[26]; const float* gc2b = (const float*)d_in[27];
    const float* ln2g = (const float*)d_in[28]; const float* ln2b = (const float*)d_in[29];
    const float* cv3w = (const float*)d_in[30]; const float* cv3b = (const float*)d_in[31];
    const float* ow  = (const float*)d_in[32]; const float* ob  = (const float*)d_in[33];
    float* out = (float*)d_out;

    const int N = in_sizes[0] / 3;
    const int E = in_sizes[1] / 2;
    const int* srcI = ei;
    const int* dstI = ei + E;

    char* base = (char*)d_ws;
    size_t off = 0;
    auto take = [&](size_t bytes) -> char* {
        char* p = base + off;
        off = (off + bytes + 255) & ~(size_t)255;
        return p;
    };
    int*   deg    = (int*)  take((size_t)N * 4);
    float* dinv   = (float*)take((size_t)N * 4);
    int*   startv = (int*)  take((size_t)N * 4);
    int*   rank   = (int*)  take((size_t)E * 4);
    int*   csr    = (int*)  take((size_t)E * 4);
    int*   bsum   = (int*)  take(512 * 4);
    float* sm     = (float*)take(8192 * 4);
    unsigned short* WB = (unsigned short*)take(278528 * 2);
    unsigned short* H  = (unsigned short*)take((size_t)N * 320 * 2);
    float* F1 = (float*)take((size_t)N * 128 * 4);
    unsigned short* B1 = (unsigned short*)take((size_t)N * 64 * 2);
    unsigned short* B2 = (unsigned short*)take((size_t)N * 128 * 2);
    unsigned short* B3 = (unsigned short*)take((size_t)N * 128 * 2);

    unsigned short* c2wb  = WB + 0;
    unsigned short* c3wb  = WB + 8192;
    unsigned short* li1wb = WB + 139264;
    unsigned short* gc1wb = WB + 143360;
    unsigned short* cv2wb = WB + 147456;
    unsigned short* li2wb = WB + 163840;
    unsigned short* gc2wb = WB + 180224;
    unsigned short* cv3wb = WB + 196608;

    float* sum2 = sm + 0;    float* ss2 = sm + 128;
    float* sum3 = sm + 256;  float* ss3 = sm + 1280;
    unsigned* maxk = (unsigned*)(sm + 2304);
    float* pooled = sm + 3328;
    unsigned* dmax = (unsigned*)(sm + 3584);
    float* T9  = sm + 3968; float* c4 = sm + 3984;
    float* a1  = sm + 5120;

    const float invn = 1.0f / (float)N;
    const dim3 blk(256);
    const unsigned GX = (unsigned)(N / 128);
    const unsigned NB = cdivu((unsigned)N, 256);

    hipMemsetAsync(deg, 0, (size_t)N * 4, stream);
    hipMemsetAsync(sm, 0, 3712 * 4, stream);

    // ---- graph prep ----
    k_degrank<<<cdivu(E, 256), blk, 0, stream>>>(dstI, deg, rank, E);
    k_scan_local<<<NB, blk, 0, stream>>>(deg, startv, bsum, dinv, N);
    k_scan_bsum<<<1, 512, 0, stream>>>(bsum, (int)NB);
    k_scan_add<<<NB, blk, 0, stream>>>(startv, bsum, N);
    k_fill<<<cdivu(E, 256), blk, 0, stream>>>(srcI, dstI, rank, startv, csr, E);

    k_wconv<<<cdivu(278528, 256), blk, 0, stream>>>(c2w, c3w, li1w, gc1w, cv2w, li2w, gc2w, cv3w, WB);

    // ---- TNet ----
    k_h1<<<cdivu((unsigned)N, 256), blk, 0, stream>>>(x, c1w, c1b, B1, N);
    k_mgemm<128, (MF_BIAS | MF_STOREF | MF_STATS)><<<dim3(GX, 1), blk, 0, stream>>>(
        B1, 64, 64, c2wb, c2b, F1, nullptr, 128, nullptr, sum2, ss2, dmax);
    k_prebn<<<cdivu((unsigned)N * 128 / 4, 256), blk, 0, stream>>>(F1, sum2, ss2, B2, N * 128, invn);
    k_z3<<<8 * GX, blk, 0, stream>>>(B2, c3wb, c3b, sum3, ss3, maxk, (int)GX);
    k_fc1<<<8, blk, 0, stream>>>(sum3, ss3, maxk, f1w, f1b, a1, invn);
    k_fc23<<<1, blk, 0, stream>>>(a1, f2w, f2b, f3w, f3b, T9);
    k_xg<<<cdivu((unsigned)N, 256), blk, 0, stream>>>(x, T9, cv1w, cv1b, H + 256, N);

    // ---- GCN block 1 (C=64) ----
    k_ligc<64><<<GX, blk, 0, stream>>>(H + 256, 320, 64, li1wb, li1b, gc1wb, dinv, B1, 64, B2, 64);
    k_gln<64><<<cdivu((unsigned)N, 4), blk, 0, stream>>>(
        startv, deg, csr, B2, B1, dinv, gc1b, ln1g, ln1b, B3, 128, N);
    k_mgemm<128, (MF_BIAS | MF_LRELU | MF_STOREB)><<<dim3(GX, 1), blk, 0, stream>>>(
        B3, 128, 128, cv2wb, cv2b, nullptr, B2, 128, nullptr, nullptr, nullptr, nullptr);

    // ---- GCN block 2 (C=128) ----
    k_ligc<128><<<GX, blk, 0, stream>>>(B2, 128, 128, li2wb, li2b, gc2wb, dinv, B3, 128, B2, 128);
    k_gln<128><<<cdivu((unsigned)N, 4), blk, 0, stream>>>(
        startv, deg, csr, B2, B3, dinv, gc2b, ln2g, ln2b, H, 320, N);

    // ---- conv3 (K=320 -> 256) fused column-sum only ----
    k_mgemm<128, (MF_BIAS | MF_LRELU | MF_COLSUM)><<<dim3(GX, 2), blk, 0, stream>>>(
        H, 320, 320, cv3wb, cv3b, nullptr, nullptr, 0, nullptr, pooled, nullptr, nullptr);

    // ---- head ----
    k_const4<<<1, 256, 0, stream>>>(pooled, ow, ob, c4, invn);
    k_out<<<cdivu((unsigned)N, 256), blk, 0, stream>>>(H, ow, c4, out, N);
}

// Round 11
// 544.234 us; speedup vs baseline: 1.1181x; 1.0394x over previous
//
#include <hip/hip_runtime.h>
#include <cstddef>

#define EPSV 1e-5f

typedef __attribute__((ext_vector_type(8))) short frag8;   // 8 bf16 (4 VGPRs)
typedef __attribute__((ext_vector_type(4))) float f32x4;   // MFMA acc

__device__ __forceinline__ float lrelu01(float v) { return v > 0.f ? v : 0.01f * v; }
__device__ __forceinline__ void atomAddF(float* p, float v) { unsafeAtomicAdd(p, v); }
__device__ __forceinline__ unsigned fkey(float f) {
    unsigned u = __float_as_uint(f);
    return (u & 0x80000000u) ? ~u : (u | 0x80000000u);
}
__device__ __forceinline__ unsigned short f2b(float f) {  // RNE float->bf16
    unsigned u = __float_as_uint(f);
    unsigned r = u + 0x7fffu + ((u >> 16) & 1u);
    return (unsigned short)(r >> 16);
}
__device__ __forceinline__ float b2f(unsigned short h) {
    return __uint_as_float(((unsigned)h) << 16);
}
__device__ __forceinline__ float blo(unsigned u) { return __uint_as_float(u << 16); }
__device__ __forceinline__ float bhi(unsigned u) { return __uint_as_float(u & 0xffff0000u); }

static inline unsigned cdivu(unsigned a, unsigned b) { return (a + b - 1) / b; }

// ---------------- graph prep: degree+rank, dinv, CSR build ----------------

__global__ void k_degrank(const int* __restrict__ dst, int* __restrict__ deg,
                          int* __restrict__ rank, int E) {
    int e = blockIdx.x * 256 + threadIdx.x;
    if (e < E) rank[e] = atomicAdd(&deg[dst[e]], 1);
}

// scan of deg -> startv (local) + block sums; fused dinv = rsqrt(deg+1)
__global__ void k_scan_local(const int* __restrict__ deg, int* __restrict__ startv,
                             int* __restrict__ bsum, float* __restrict__ dinv, int n) {
    __shared__ int t0[256];
    int tid = threadIdx.x;
    int i = blockIdx.x * 256 + tid;
    int v = (i < n) ? deg[i] : 0;
    if (i < n) dinv[i] = rsqrtf((float)(v + 1));  // +1 self loop
    t0[tid] = v;
    __syncthreads();
    for (int o = 1; o < 256; o <<= 1) {
        int add = (tid >= o) ? t0[tid - o] : 0;
        __syncthreads();
        t0[tid] += add;
        __syncthreads();
    }
    if (i < n) startv[i] = t0[tid] - v;
    if (tid == 255) bsum[blockIdx.x] = t0[255];
}

__global__ void k_scan_bsum(int* __restrict__ bsum, int nb) {
    __shared__ int t0[512];
    int tid = threadIdx.x;
    int v = (tid < nb) ? bsum[tid] : 0;
    t0[tid] = v;
    __syncthreads();
    for (int o = 1; o < 512; o <<= 1) {
        int add = (tid >= o) ? t0[tid - o] : 0;
        __syncthreads();
        t0[tid] += add;
        __syncthreads();
    }
    if (tid < nb) bsum[tid] = t0[tid] - v;
}

__global__ void k_scan_add(int* __restrict__ startv, const int* __restrict__ bsum, int n) {
    int i = blockIdx.x * 256 + threadIdx.x;
    if (i < n) startv[i] += bsum[blockIdx.x];
}

__global__ void k_fill(const int* __restrict__ src, const int* __restrict__ dst,
                       const int* __restrict__ rank, const int* __restrict__ startv,
                       int* __restrict__ csr, int E) {
    int e = blockIdx.x * 256 + threadIdx.x;
    if (e < E) csr[startv[dst[e]] + rank[e]] = src[e];
}

// ---------------- fused gather + LN (16-lane groups, dwordx4 rows) ----------------
template <int CH>
__launch_bounds__(256)
__global__ void k_gln(const int* __restrict__ startv, const int* __restrict__ degv,
                      const int* __restrict__ csr, const unsigned short* __restrict__ q,
                      const unsigned short* __restrict__ nf, const float* __restrict__ dinv,
                      const float* __restrict__ gcn_b, const float* __restrict__ lng,
                      const float* __restrict__ lnb, unsigned short* __restrict__ outp,
                      int ldo, int n) {
    const int wv = threadIdx.x >> 6, lane = threadIdx.x & 63;
    const int g = lane >> 4, p = lane & 15;
    int node = blockIdx.x * 4 + wv;
    if (node >= n) return;
    constexpr int CPL = CH / 16;   // channels per lane
    constexpr int DPL = CPL / 2;   // dwords per lane per row

    float acc[CPL];
#pragma unroll
    for (int k = 0; k < CPL; ++k) acc[k] = 0.f;

    {
        unsigned su[DPL];
        const unsigned short* qrow = q + (size_t)node * CH + p * CPL;
        if (DPL == 4) *(uint4*)su = *(const uint4*)qrow;
        else          *(uint2*)su = *(const uint2*)qrow;
        if (g == 0) {
#pragma unroll
            for (int d = 0; d < DPL; ++d) { acc[2 * d] += blo(su[d]); acc[2 * d + 1] += bhi(su[d]); }
        }
    }

    int s0 = startv[node], cnt = degv[node];
    int sidx[4];
#pragma unroll
    for (int t = 0; t < 4; ++t) { int j = t * 4 + g; sidx[t] = (j < cnt) ? csr[s0 + j] : 0; }
    for (int j0 = 0; j0 < cnt; j0 += 16) {
        unsigned buf[4][DPL];
#pragma unroll
        for (int t = 0; t < 4; ++t) {
            const unsigned short* src = q + (size_t)sidx[t] * CH + p * CPL;
            if (DPL == 4) *(uint4*)buf[t] = *(const uint4*)src;
            else          *(uint2*)buf[t] = *(const uint2*)src;
        }
        int nsidx[4];
#pragma unroll
        for (int t = 0; t < 4; ++t) {
            int j = j0 + 16 + t * 4 + g;
            nsidx[t] = (j < cnt) ? csr[s0 + j] : 0;
        }
#pragma unroll
        for (int t = 0; t < 4; ++t) {
            if (j0 + t * 4 + g < cnt) {
#pragma unroll
                for (int d = 0; d < DPL; ++d) {
                    acc[2 * d] += blo(buf[t][d]);
                    acc[2 * d + 1] += bhi(buf[t][d]);
                }
            }
        }
#pragma unroll
        for (int t = 0; t < 4; ++t) sidx[t] = nsidx[t];
    }

#pragma unroll
    for (int k = 0; k < CPL; ++k) {
        acc[k] += __shfl_xor(acc[k], 16);
        acc[k] += __shfl_xor(acc[k], 32);
    }

    float di = dinv[node];
    float nv[CPL], bv[CPL];
    {
        unsigned su[DPL];
        const unsigned short* nrow = nf + (size_t)node * CH + p * CPL;
        if (DPL == 4) *(uint4*)su = *(const uint4*)nrow;
        else          *(uint2*)su = *(const uint2*)nrow;
#pragma unroll
        for (int d = 0; d < DPL; ++d) { nv[2 * d] = blo(su[d]); nv[2 * d + 1] = bhi(su[d]); }
    }
    const float* gb = gcn_b + p * CPL;
#pragma unroll
    for (int k = 0; k < CPL; ++k) bv[k] = lrelu01(di * acc[k] + gb[k]);

    float s = 0.f, ss = 0.f;
#pragma unroll
    for (int k = 0; k < CPL; ++k) { s += nv[k] + bv[k]; ss += nv[k] * nv[k] + bv[k] * bv[k]; }
#pragma unroll
    for (int off = 32; off > 0; off >>= 1) { s += __shfl_xor(s, off); ss += __shfl_xor(ss, off); }
    const float inv = 1.f / (float)(8 * CH);  // 4x group replication * 2*CH channels
    float mu = s * inv;
    float var = ss * inv - mu * mu;
    float rsg = rsqrtf(var + EPSV);

    unsigned short* orow = outp + (size_t)node * ldo;
    if (g == 0) {
        unsigned short tmp[CPL];
        const float* lg = lng + p * CPL; const float* lb = lnb + p * CPL;
#pragma unroll
        for (int k = 0; k < CPL; ++k) tmp[k] = f2b((nv[k] - mu) * rsg * lg[k] + lb[k]);
        if (DPL == 4) *(uint4*)(orow + p * CPL) = *(uint4*)tmp;
        else          *(uint2*)(orow + p * CPL) = *(uint2*)tmp;
    } else if (g == 1) {
        unsigned short tmp[CPL];
        const float* lg = lng + CH + p * CPL; const float* lb = lnb + CH + p * CPL;
#pragma unroll
        for (int k = 0; k < CPL; ++k) tmp[k] = f2b((bv[k] - mu) * rsg * lg[k] + lb[k]);
        if (DPL == 4) *(uint4*)(orow + CH + p * CPL) = *(uint4*)tmp;
        else          *(uint2*)(orow + CH + p * CPL) = *(uint2*)tmp;
    }
}

// ---------------- small kernels ----------------

// weight fp32->bf16 pack; the c3 segment (seg 1) is additionally permuted into
// MFMA fragment order (8 tiles of 128ch x 128k) so k_z3 can load fragments
// directly from global with no LDS staging.
__global__ void k_wconv(const float* __restrict__ s0, const float* __restrict__ s1,
                        const float* __restrict__ s2, const float* __restrict__ s3,
                        const float* __restrict__ s4, const float* __restrict__ s5,
                        const float* __restrict__ s6, const float* __restrict__ s7,
                        unsigned short* __restrict__ dst) {
    int t = blockIdx.x * 256 + threadIdx.x;
    if (t >= 278528) return;
    const float* srcs[8] = {s0, s1, s2, s3, s4, s5, s6, s7};
    const int off[9] = {0, 8192, 139264, 143360, 147456, 163840, 180224, 196608, 278528};
    int seg = 0;
    while (t >= off[seg + 1]) ++seg;
    unsigned short v = f2b(srcs[seg][t - off[seg]]);
    if (seg == 1) {
        int li = t - 8192;
        int rch = li >> 7, k = li & 127;
        int cb = rch >> 7, r = rch & 127;
        int flat = ((r >> 4) * 4 + (k >> 5)) * 64 + ((k >> 3) & 3) * 16 + (r & 15);
        dst[8192 + cb * 16384 + flat * 8 + (k & 7)] = v;
    } else {
        dst[t] = v;
    }
}

__global__ void k_h1(const float* __restrict__ x, const float* __restrict__ w,
                     const float* __restrict__ b, unsigned short* __restrict__ h1, int n) {
    int node = blockIdx.x * 256 + threadIdx.x;
    if (node >= n) return;
    float x0 = x[node * 3], x1 = x[node * 3 + 1], x2 = x[node * 3 + 2];
    unsigned short* o = h1 + (size_t)node * 64;
#pragma unroll
    for (int cp = 0; cp < 8; ++cp) {
        unsigned short tmp[8];
#pragma unroll
        for (int t = 0; t < 8; ++t) {
            int c = cp * 8 + t;
            float v = x0 * w[c * 3] + x1 * w[c * 3 + 1] + x2 * w[c * 3 + 2] + b[c];
            tmp[t] = f2b(fmaxf(v, 0.f));
        }
        *(float4*)(o + cp * 8) = *(float4*)tmp;
    }
}

// A3F = bf16(relu((z2 - mu)*rs)) written in per-tile MFMA fragment order.
// thread t: node row = t>>4, 8-channel chunk cp = t&15.
__global__ void k_prebn(const float* __restrict__ z, const float* __restrict__ sum2,
                        const float* __restrict__ ss2, unsigned short* __restrict__ a3f,
                        int n16, float invn) {
    int t = blockIdx.x * 256 + threadIdx.x;
    if (t >= n16) return;
    int row = t >> 4, cp = t & 15;
    int c = cp * 8;
    const float* src = z + (size_t)row * 128 + c;
    float4 v0 = *(const float4*)src;
    float4 v1 = *(const float4*)(src + 4);
    float vv[8] = {v0.x, v0.y, v0.z, v0.w, v1.x, v1.y, v1.z, v1.w};
    unsigned short o[8];
#pragma unroll
    for (int i = 0; i < 8; ++i) {
        float m = sum2[c + i] * invn;
        float var = ss2[c + i] * invn - m * m;
        o[i] = f2b(fmaxf((vv[i] - m) * rsqrtf(var + EPSV), 0.f));
    }
    int tile = row >> 7, r = row & 127;
    int flat = ((r >> 4) * 4 + (cp >> 2)) * 64 + (cp & 3) * 16 + (r & 15);
    *(float4*)(a3f + (size_t)tile * 16384 + flat * 8) = *(float4*)o;
}

// fc1 with fused g-compute: g[c]=relu((max-mu)*rsqrt(var+eps)) built in LDS per block
__launch_bounds__(256)
__global__ void k_fc1(const float* __restrict__ sum3, const float* __restrict__ ss3,
                      const unsigned* __restrict__ maxk,
                      const float* __restrict__ f1w, const float* __restrict__ f1b,
                      float* __restrict__ a1, float invn) {
    __shared__ float g[1024];
    int tid = threadIdx.x;
    for (int c = tid; c < 1024; c += 256) {
        float m = sum3[c] * invn;
        float var = ss3[c] * invn - m * m;
        unsigned k = maxk[c];
        unsigned u = (k & 0x80000000u) ? (k & 0x7FFFFFFFu) : ~k;
        g[c] = fmaxf((__uint_as_float(u) - m) * rsqrtf(var + EPSV), 0.f);
    }
    __syncthreads();
    int row = blockIdx.x * 64 + (tid >> 2);
    int part = tid & 3;
    const float* w = f1w + (size_t)row * 1024 + part * 256;
    const float* gg = g + part * 256;
    float s = 0.f;
    for (int k = 0; k < 256; ++k) s = fmaf(w[k], gg[k], s);
    s += __shfl_xor(s, 1); s += __shfl_xor(s, 2);
    if (part == 0) a1[row] = fmaxf(s + f1b[row], 0.f);
}

__launch_bounds__(256)
__global__ void k_fc23(const float* __restrict__ a1, const float* __restrict__ f2w,
                       const float* __restrict__ f2b, const float* __restrict__ f3w,
                       const float* __restrict__ f3b, float* __restrict__ T9) {
    __shared__ float a2[256];
    int tid = threadIdx.x;
    {
        const float* w = f2w + (size_t)tid * 512;
        float s = f2b[tid];
        for (int k = 0; k < 512; ++k) s = fmaf(w[k], a1[k], s);
        a2[tid] = fmaxf(s, 0.f);
    }
    __syncthreads();
    if (tid < 9) {
        const float* w = f3w + (size_t)tid * 256;
        float s = f3b[tid];
        for (int k = 0; k < 256; ++k) s = fmaf(w[k], a2[k], s);
        if (tid == 0 || tid == 4 || tid == 8) s += 1.f;
        T9[tid] = s;
    }
}

__global__ void k_xg(const float* __restrict__ x, const float* __restrict__ T9,
                     const float* __restrict__ w, const float* __restrict__ b,
                     unsigned short* __restrict__ xg, int n) {
    int node = blockIdx.x * 256 + threadIdx.x;
    if (node >= n) return;
    float x0 = x[node * 3], x1 = x[node * 3 + 1], x2 = x[node * 3 + 2];
    float h0 = x0 * T9[0] + x1 * T9[3] + x2 * T9[6];
    float h1 = x0 * T9[1] + x1 * T9[4] + x2 * T9[7];
    float h2 = x0 * T9[2] + x1 * T9[5] + x2 * T9[8];
    unsigned short* o = xg + (size_t)node * 320;
#pragma unroll
    for (int cp = 0; cp < 8; ++cp) {
        unsigned short tmp[8];
#pragma unroll
        for (int t = 0; t < 8; ++t) {
            int c = cp * 8 + t;
            float v = h0 * w[c * 3] + h1 * w[c * 3 + 1] + h2 * w[c * 3 + 2] + b[c];
            tmp[t] = f2b(lrelu01(v));
        }
        *(float4*)(o + cp * 8) = *(float4*)tmp;
    }
}

__global__ void k_const4(const float* __restrict__ pooled, const float* __restrict__ ow,
                         const float* __restrict__ ob, float* __restrict__ c4, float invn) {
    int j = threadIdx.x >> 6, lane = threadIdx.x & 63;
    float s = 0.f;
    for (int c = lane; c < 256; c += 64) s += pooled[c] * invn * ow[j * 320 + c];
#pragma unroll
    for (int off = 32; off > 0; off >>= 1) s += __shfl_down(s, off);
    if (lane == 0) c4[j] = s + ob[j];
}

__global__ void k_out(const unsigned short* __restrict__ hcat, const float* __restrict__ ow,
                      const float* __restrict__ c4, float* __restrict__ out, int n) {
    int node = blockIdx.x * 256 + threadIdx.x;
    if (node >= n) return;
    const unsigned short* xgp = hcat + (size_t)node * 320 + 256;
    float s0 = c4[0], s1 = c4[1], s2 = c4[2], s3 = c4[3];
#pragma unroll
    for (int cp = 0; cp < 8; ++cp) {
        float4 raw = *(const float4*)(xgp + cp * 8);
        unsigned short tmp[8];
        *(float4*)tmp = raw;
#pragma unroll
        for (int t = 0; t < 8; ++t) {
            int k = 256 + cp * 8 + t;
            float f = b2f(tmp[t]);
            s0 = fmaf(f, ow[k], s0);
            s1 = fmaf(f, ow[320 + k], s1);
            s2 = fmaf(f, ow[640 + k], s2);
            s3 = fmaf(f, ow[960 + k], s3);
        }
    }
    *(float4*)(out + (size_t)node * 4) = make_float4(s0, s1, s2, s3);
}

// ---------------- MFMA bf16 GEMM (generic, BK=32) ----------------
enum { MF_BIAS = 1, MF_LRELU = 2, MF_DINV = 4, MF_STOREF = 8, MF_STOREB = 16,
       MF_STATS = 32, MF_COLSUM = 64 };

template <int BN, int MODE>
__launch_bounds__(256)
__global__ void k_mgemm(const unsigned short* __restrict__ A, int lda, int K,
                        const unsigned short* __restrict__ W,  // [C][K]
                        const float* __restrict__ bias,
                        float* __restrict__ OutF, unsigned short* __restrict__ OutB, int ldo,
                        const float* __restrict__ dinv,
                        float* __restrict__ sum_o, float* __restrict__ ss_o,
                        unsigned* __restrict__ maxk_o) {
    constexpr int BM = 128;
    constexpr int LDT = 40;
    __shared__ unsigned short As[BM * LDT];
    __shared__ unsigned short Ws[BN * LDT];
    __shared__ float redS[2 * 128];
    __shared__ unsigned redM[128];

    const int tid = threadIdx.x;
    const int wid = tid >> 6, lane = tid & 63;
    const int quad = lane >> 4, lrow = lane & 15;
    const int bn0 = blockIdx.x * BM;
    const int bc0 = blockIdx.y * BN;

    constexpr int NI = (BN == 128) ? 4 : 2;
    constexpr int NJ = 4;
    const int wm = (BN == 128) ? (wid & 1) * 64 : wid * 32;
    const int wn = (BN == 128) ? (wid >> 1) * 64 : 0;

    if (MODE & (MF_STATS | MF_COLSUM)) {
        for (int c = tid; c < BN; c += 256) {
            redS[c] = 0.f; redS[128 + c] = 0.f; redM[c] = 0u;
        }
    }

    f32x4 acc[NI][NJ] = {};

    for (int k0 = 0; k0 < K; k0 += 32) {
#pragma unroll
        for (int h = 0; h < 2; ++h) {
            int ch = tid + h * 256;
            int row = ch >> 2, cp = ch & 3;
            const unsigned short* src = A + (size_t)(bn0 + row) * lda + k0 + cp * 8;
            *(float4*)&As[row * LDT + cp * 8] = *(const float4*)src;
        }
#pragma unroll
        for (int h = 0; h < BN / 64; ++h) {
            int ch = tid + h * 256;
            int row = ch >> 2, cp = ch & 3;
            const unsigned short* src = W + (size_t)(bc0 + row) * K + k0 + cp * 8;
            *(float4*)&Ws[row * LDT + cp * 8] = *(const float4*)src;
        }
        __syncthreads();
        frag8 af[NI], bf[NJ];
#pragma unroll
        for (int i = 0; i < NI; ++i)
            af[i] = *(const frag8*)&As[(wm + i * 16 + lrow) * LDT + quad * 8];
#pragma unroll
        for (int j = 0; j < NJ; ++j)
            bf[j] = *(const frag8*)&Ws[(wn + j * 16 + lrow) * LDT + quad * 8];
#pragma unroll
        for (int i = 0; i < NI; ++i)
#pragma unroll
            for (int j = 0; j < NJ; ++j)
                acc[i][j] = __builtin_amdgcn_mfma_f32_16x16x32_bf16(af[i], bf[j], acc[i][j], 0, 0, 0);
        __syncthreads();
    }

#pragma unroll
    for (int j = 0; j < NJ; ++j) {
        const int col = bc0 + wn + j * 16 + lrow;
        float bv = (MODE & MF_BIAS) ? bias[col] : 0.f;
        float s = 0.f, q = 0.f, m = -3.4e38f;
#pragma unroll
        for (int i = 0; i < NI; ++i) {
            const int rowb = bn0 + wm + i * 16 + quad * 4;
#pragma unroll
            for (int r = 0; r < 4; ++r) {
                float t = acc[i][j][r] + bv;
                if (MODE & MF_LRELU) t = lrelu01(t);
                if (MODE & MF_DINV) t *= dinv[rowb + r];
                if (MODE & MF_STOREF) OutF[(size_t)(rowb + r) * ldo + col] = t;
                if (MODE & MF_STOREB) OutB[(size_t)(rowb + r) * ldo + col] = f2b(t);
                s += t; q += t * t; m = fmaxf(m, t);
            }
        }
        if (MODE & (MF_STATS | MF_COLSUM)) {
            s += __shfl_xor(s, 16); s += __shfl_xor(s, 32);
            if (MODE & MF_STATS) {
                q += __shfl_xor(q, 16); q += __shfl_xor(q, 32);
                m = fmaxf(m, __shfl_xor(m, 16)); m = fmaxf(m, __shfl_xor(m, 32));
            }
            if (quad == 0) {
                int lc = wn + j * 16 + lrow;
                atomicAdd(&redS[lc], s);
                if (MODE & MF_STATS) {
                    atomicAdd(&redS[128 + lc], q);
                    atomicMax(&redM[lc], fkey(m));
                }
            }
        }
    }
    if (MODE & (MF_STATS | MF_COLSUM)) {
        __syncthreads();
        for (int c = tid; c < BN; c += 256) {
            atomAddF(&sum_o[bc0 + c], redS[c]);
            if (MODE & MF_STATS) {
                atomAddF(&ss_o[bc0 + c], redS[128 + c]);
                atomicMax(&maxk_o[bc0 + c], redM[c]);
            }
        }
    }
}

// ---------------- fused li+gc ----------------
template <int BN>
__launch_bounds__(256)
__global__ void k_ligc(const unsigned short* __restrict__ A, int lda, int K,
                       const unsigned short* __restrict__ Wli, const float* __restrict__ bli,
                       const unsigned short* __restrict__ Wgc, const float* __restrict__ dinv,
                       unsigned short* __restrict__ NF, int ldnf,
                       unsigned short* __restrict__ Q, int ldq) {
    constexpr int BM = 128;
    constexpr int LDT = 40;
    constexpr int LDT2 = BN + 8;
    __shared__ unsigned short SA[BM * LDT2];
    __shared__ unsigned short Ws[BN * LDT];

    const int tid = threadIdx.x;
    const int wid = tid >> 6, lane = tid & 63;
    const int quad = lane >> 4, lrow = lane & 15;
    const int bn0 = blockIdx.x * BM;
    constexpr int NI = (BN == 128) ? 4 : 2;
    constexpr int NJ = 4;
    const int wm = (BN == 128) ? (wid & 1) * 64 : wid * 32;
    const int wn = (BN == 128) ? (wid >> 1) * 64 : 0;

    {
        f32x4 acc[NI][NJ] = {};
        for (int k0 = 0; k0 < K; k0 += 32) {
#pragma unroll
            for (int h = 0; h < 2; ++h) {
                int ch = tid + h * 256;
                int row = ch >> 2, cp = ch & 3;
                *(float4*)&SA[row * LDT + cp * 8] =
                    *(const float4*)(A + (size_t)(bn0 + row) * lda + k0 + cp * 8);
            }
#pragma unroll
            for (int h = 0; h < BN / 64; ++h) {
                int ch = tid + h * 256;
                int row = ch >> 2, cp = ch & 3;
                *(float4*)&Ws[row * LDT + cp * 8] =
                    *(const float4*)(Wli + (size_t)row * K + k0 + cp * 8);
            }
            __syncthreads();
            frag8 af[NI], bf[NJ];
#pragma unroll
            for (int i = 0; i < NI; ++i)
                af[i] = *(const frag8*)&SA[(wm + i * 16 + lrow) * LDT + quad * 8];
#pragma unroll
            for (int j = 0; j < NJ; ++j)
                bf[j] = *(const frag8*)&Ws[(wn + j * 16 + lrow) * LDT + quad * 8];
#pragma unroll
            for (int i = 0; i < NI; ++i)
#pragma unroll
                for (int j = 0; j < NJ; ++j)
                    acc[i][j] = __builtin_amdgcn_mfma_f32_16x16x32_bf16(af[i], bf[j], acc[i][j], 0, 0, 0);
            __syncthreads();
        }
#pragma unroll
        for (int j = 0; j < NJ; ++j) {
            const int col = wn + j * 16 + lrow;
            float bv = bli[col];
#pragma unroll
            for (int i = 0; i < NI; ++i) {
                const int rowl = wm + i * 16 + quad * 4;
#pragma unroll
                for (int r = 0; r < 4; ++r) {
                    unsigned short h = f2b(lrelu01(acc[i][j][r] + bv));
                    NF[(size_t)(bn0 + rowl + r) * ldnf + col] = h;
                    SA[(rowl + r) * LDT2 + col] = h;
                }
            }
        }
        __syncthreads();
    }
    {
        f32x4 acc[NI][NJ] = {};
        for (int k0 = 0; k0 < BN; k0 += 32) {
#pragma unroll
            for (int h = 0; h < BN / 64; ++h) {
                int ch = tid + h * 256;
                int row = ch >> 2, cp = ch & 3;
                *(float4*)&Ws[row * LDT + cp * 8] =
                    *(const float4*)(Wgc + (size_t)row * BN + k0 + cp * 8);
            }
            __syncthreads();
            frag8 af[NI], bf[NJ];
#pragma unroll
            for (int i = 0; i < NI; ++i)
                af[i] = *(const frag8*)&SA[(wm + i * 16 + lrow) * LDT2 + k0 + quad * 8];
#pragma unroll
            for (int j = 0; j < NJ; ++j)
                bf[j] = *(const frag8*)&Ws[(wn + j * 16 + lrow) * LDT + quad * 8];
#pragma unroll
            for (int i = 0; i < NI; ++i)
#pragma unroll
                for (int j = 0; j < NJ; ++j)
                    acc[i][j] = __builtin_amdgcn_mfma_f32_16x16x32_bf16(af[i], bf[j], acc[i][j], 0, 0, 0);
            __syncthreads();
        }
#pragma unroll
        for (int j = 0; j < NJ; ++j) {
            const int col = wn + j * 16 + lrow;
#pragma unroll
            for (int i = 0; i < NI; ++i) {
                const int rowb = bn0 + wm + i * 16 + quad * 4;
#pragma unroll
                for (int r = 0; r < 4; ++r) {
                    float t = acc[i][j][r] * dinv[rowb + r];
                    Q[(size_t)(rowb + r) * ldq + col] = f2b(t);
                }
            }
        }
    }
}

// ---------------- z3 stats GEMM v5: no LDS, no barrier ----------------
// A3F and WF are pre-permuted into MFMA fragment order in global memory, so each
// wave loads its fragments directly (coalesced 16 B/lane). XCD swizzle retained.
__launch_bounds__(256)
__global__ void k_z3(const unsigned short* __restrict__ AF,  // [ntiles][16384] frag order
                     const unsigned short* __restrict__ WF,  // [8][16384] frag order (c3)
                     const float* __restrict__ bias,         // [1024]
                     float* __restrict__ sum_o, float* __restrict__ ss_o,
                     unsigned* __restrict__ maxk_o, int ntiles) {
    const int tid = threadIdx.x;
    const int wid = tid >> 6, lane = tid & 63;
    const int quad = lane >> 4, lrow = lane & 15;

    int bid = blockIdx.x;
    int w = (bid & 7) * ntiles + (bid >> 3);  // XCD = bid%8 -> contiguous tile range
    const int tile = w >> 3;
    const int cb = w & 7;
    const unsigned short* At = AF + (size_t)tile * 16384;
    const unsigned short* Wt = WF + (size_t)cb * 16384;

    const int ar = (wid & 1) * 4;   // A row-subtile base (16-row units)
    const int wc = (wid >> 1) * 4;  // W col-subtile base
    f32x4 acc[4][4] = {};
#pragma unroll
    for (int kc = 0; kc < 4; ++kc) {
        frag8 af[4], bf[4];
#pragma unroll
        for (int i = 0; i < 4; ++i)
            af[i] = *(const frag8*)&At[(((ar + i) * 4 + kc) * 64 + lane) * 8];
#pragma unroll
        for (int j = 0; j < 4; ++j)
            bf[j] = *(const frag8*)&Wt[(((wc + j) * 4 + kc) * 64 + lane) * 8];
#pragma unroll
        for (int i = 0; i < 4; ++i)
#pragma unroll
            for (int j = 0; j < 4; ++j)
                acc[i][j] = __builtin_amdgcn_mfma_f32_16x16x32_bf16(af[i], bf[j], acc[i][j], 0, 0, 0);
    }

#pragma unroll
    for (int j = 0; j < 4; ++j) {
        int c = cb * 128 + (wc + j) * 16 + lrow;
        float bv = bias[c];
        float s = 0.f, q = 0.f, m = -3.4e38f;
#pragma unroll
        for (int i = 0; i < 4; ++i)
#pragma unroll
            for (int r = 0; r < 4; ++r) {
                float t = acc[i][j][r] + bv;
                s += t; q += t * t; m = fmaxf(m, t);
            }
        s += __shfl_xor(s, 16); s += __shfl_xor(s, 32);
        q += __shfl_xor(q, 16); q += __shfl_xor(q, 32);
        m = fmaxf(m, __shfl_xor(m, 16)); m = fmaxf(m, __shfl_xor(m, 32));
        if (quad == 0) {
            atomAddF(&sum_o[c], s);
            atomAddF(&ss_o[c], q);
            atomicMax(&maxk_o[c], fkey(m));
        }
    }
}

// ---------------- launch ----------------
// Buffer lifetimes:
//   F1 [N,128]f32: z2 only
//   B1 [N,64] u16: h1 -> nf1
//   B2 [N,128]u16: A3F (fragment order) -> q1 (first N*64) -> hmid -> q2 (in-place)
//   B3 [N,128]u16: hln1 -> nf2
//   H  [N,320]u16: xg cols 256.. (early), LN2 out cols 0..255 (late)

extern "C" void kernel_launch(void* const* d_in, const int* in_sizes, int n_in,
                              void* d_out, int out_size, void* d_ws, size_t ws_size,
                              hipStream_t stream) {
    const float* x   = (const float*)d_in[0];
    const int*   ei  = (const int*)d_in[1];
    const float* c1w = (const float*)d_in[2];  const float* c1b = (const float*)d_in[3];
    const float* c2w = (const float*)d_in[4];  const float* c2b = (const float*)d_in[5];
    const float* c3w = (const float*)d_in[6];  const float* c3b = (const float*)d_in[7];
    const float* f1w = (const float*)d_in[8];  const float* f1b = (const float*)d_in[9];
    const float* f2w = (const float*)d_in[10]; const float* f2b = (const float*)d_in[11];
    const float* f3w = (const float*)d_in[12]; const float* f3b = (const float*)d_in[13];
    const float* cv1w = (const float*)d_in[14]; const float* cv1b = (const float*)d_in[15];
    const float* li1w = (const float*)d_in[16]; const float* li1b = (const float*)d_in[17];
    const float* gc1w = (const float*)d_in[18]; const float* gc1b = (const float*)d_in[19];
    const float* ln1g = (const float*)d_in[20]; const float* ln1b = (const float*)d_in[21];
    const float* cv2w = (const float*)d_in[22]; const float* cv2b = (const float*)d_in[23];
    const float* li2w = (const float*)d_in[24]; const float* li2b = (const float*)d_in[25];
    const float* gc2w = (const float*)d_in[26]; const float* gc2b = (const float*)d_in[27];
    const float* ln2g = (const float*)d_in[28]; const float* ln2b = (const float*)d_in[29];
    const float* cv3w = (const float*)d_in[30]; const float* cv3b = (const float*)d_in[31];
    const float* ow  = (const float*)d_in[32]; const float* ob  = (const float*)d_in[33];
    float* out = (float*)d_out;

    const int N = in_sizes[0] / 3;
    const int E = in_sizes[1] / 2;
    const int* srcI = ei;
    const int* dstI = ei + E;

    char* base = (char*)d_ws;
    size_t off = 0;
    auto take = [&](size_t bytes) -> char* {
        char* p = base + off;
        off = (off + bytes + 255) & ~(size_t)255;
        return p;
    };
    int*   deg    = (int*)  take((size_t)N * 4);
    float* dinv   = (float*)take((size_t)N * 4);
    int*   startv = (int*)  take((size_t)N * 4);
    int*   rank   = (int*)  take((size_t)E * 4);
    int*   csr    = (int*)  take((size_t)E * 4);
    int*   bsum   = (int*)  take(512 * 4);
    float* sm     = (float*)take(8192 * 4);
    unsigned short* WB = (unsigned short*)take(278528 * 2);
    unsigned short* H  = (unsigned short*)take((size_t)N * 320 * 2);
    float* F1 = (float*)take((size_t)N * 128 * 4);
    unsigned short* B1 = (unsigned short*)take((size_t)N * 64 * 2);
    unsigned short* B2 = (unsigned short*)take((size_t)N * 128 * 2);
    unsigned short* B3 = (unsigned short*)take((size_t)N * 128 * 2);

    unsigned short* c2wb  = WB + 0;
    unsigned short* c3wf  = WB + 8192;   // fragment-order c3 weights (8 x 16384)
    unsigned short* li1wb = WB + 139264;
    unsigned short* gc1wb = WB + 143360;
    unsigned short* cv2wb = WB + 147456;
    unsigned short* li2wb = WB + 163840;
    unsigned short* gc2wb = WB + 180224;
    unsigned short* cv3wb = WB + 196608;

    float* sum2 = sm + 0;    float* ss2 = sm + 128;
    float* sum3 = sm + 256;  float* ss3 = sm + 1280;
    unsigned* maxk = (unsigned*)(sm + 2304);
    float* pooled = sm + 3328;
    unsigned* dmax = (unsigned*)(sm + 3584);
    float* T9  = sm + 3968; float* c4 = sm + 3984;
    float* a1  = sm + 5120;

    const float invn = 1.0f / (float)N;
    const dim3 blk(256);
    const unsigned GX = (unsigned)(N / 128);
    const unsigned NB = cdivu((unsigned)N, 256);

    hipMemsetAsync(deg, 0, (size_t)N * 4, stream);
    hipMemsetAsync(sm, 0, 3712 * 4, stream);

    // ---- graph prep ----
    k_degrank<<<cdivu(E, 256), blk, 0, stream>>>(dstI, deg, rank, E);
    k_scan_local<<<NB, blk, 0, stream>>>(deg, startv, bsum, dinv, N);
    k_scan_bsum<<<1, 512, 0, stream>>>(bsum, (int)NB);
    k_scan_add<<<NB, blk, 0, stream>>>(startv, bsum, N);
    k_fill<<<cdivu(E, 256), blk, 0, stream>>>(srcI, dstI, rank, startv, csr, E);

    k_wconv<<<cdivu(278528, 256), blk, 0, stream>>>(c2w, c3w, li1w, gc1w, cv2w, li2w, gc2w, cv3w, WB);

    // ---- TNet ----
    k_h1<<<cdivu((unsigned)N, 256), blk, 0, stream>>>(x, c1w, c1b, B1, N);
    k_mgemm<128, (MF_BIAS | MF_STOREF | MF_STATS)><<<dim3(GX, 1), blk, 0, stream>>>(
        B1, 64, 64, c2wb, c2b, F1, nullptr, 128, nullptr, sum2, ss2, dmax);
    k_prebn<<<cdivu((unsigned)N * 16, 256), blk, 0, stream>>>(F1, sum2, ss2, B2, N * 16, invn);
    k_z3<<<8 * GX, blk, 0, stream>>>(B2, c3wf, c3b, sum3, ss3, maxk, (int)GX);
    k_fc1<<<8, blk, 0, stream>>>(sum3, ss3, maxk, f1w, f1b, a1, invn);
    k_fc23<<<1, blk, 0, stream>>>(a1, f2w, f2b, f3w, f3b, T9);
    k_xg<<<cdivu((unsigned)N, 256), blk, 0, stream>>>(x, T9, cv1w, cv1b, H + 256, N);

    // ---- GCN block 1 (C=64) ----
    k_ligc<64><<<GX, blk, 0, stream>>>(H + 256, 320, 64, li1wb, li1b, gc1wb, dinv, B1, 64, B2, 64);
    k_gln<64><<<cdivu((unsigned)N, 4), blk, 0, stream>>>(
        startv, deg, csr, B2, B1, dinv, gc1b, ln1g, ln1b, B3, 128, N);
    k_mgemm<128, (MF_BIAS | MF_LRELU | MF_STOREB)><<<dim3(GX, 1), blk, 0, stream>>>(
        B3, 128, 128, cv2wb, cv2b, nullptr, B2, 128, nullptr, nullptr, nullptr, nullptr);

    // ---- GCN block 2 (C=128) ----
    k_ligc<128><<<GX, blk, 0, stream>>>(B2, 128, 128, li2wb, li2b, gc2wb, dinv, B3, 128, B2, 128);
    k_gln<128><<<cdivu((unsigned)N, 4), blk, 0, stream>>>(
        startv, deg, csr, B2, B3, dinv, gc2b, ln2g, ln2b, H, 320, N);

    // ---- conv3 (K=320 -> 256) fused column-sum only ----
    k_mgemm<128, (MF_BIAS | MF_LRELU | MF_COLSUM)><<<dim3(GX, 2), blk, 0, stream>>>(
        H, 320, 320, cv3wb, cv3b, nullptr, nullptr, 0, nullptr, pooled, nullptr, nullptr);

    // ---- head ----
    k_const4<<<1, 256, 0, stream>>>(pooled, ow, ob, c4, invn);
    k_out<<<cdivu((unsigned)N, 256), blk, 0, stream>>>(H, ow, c4, out, N);
}